// Round 15
// 26594.235 us; speedup vs baseline: 38.5687x; 1.0406x over previous
//
#include <hip/hip_runtime.h>
#include <hip/hip_bf16.h>
#include <math.h>

#define ACT_NONE 0
#define ACT_LEAKY 1
#define ACT_TANH 2

typedef __attribute__((ext_vector_type(8))) short bf16x8;
typedef __attribute__((ext_vector_type(4))) float f32x4;
typedef unsigned short u16;

#define MFMA(a, b, c) __builtin_amdgcn_mfma_f32_16x16x32_bf16((bf16x8)(a), (bf16x8)(b), (c), 0, 0, 0)

static inline unsigned cdivu(long a, long b) { return (unsigned)((a + b - 1) / b); }

__device__ __forceinline__ u16 f2bf(float x) {
  union { __hip_bfloat16 h; u16 u; } cv;
  cv.h = __float2bfloat16(x);
  return cv.u;
}
__device__ __forceinline__ float bf2f(u16 b) {
  union { u16 u; __hip_bfloat16 h; } cv;
  cv.u = b;
  return __bfloat162float(cv.h);
}
__device__ __forceinline__ void splitw(float v, u16* ph, u16* pl) {
  u16 h = f2bf(v);
  *ph = h;
  *pl = f2bf(v - bf2f(h));
}
// async global->LDS, 16B per lane; dest must be wave-uniform base (+lane*16)
__device__ __forceinline__ void gload16(const void* g, void* l) {
  __builtin_amdgcn_global_load_lds(
      (const __attribute__((address_space(1))) unsigned int*)g,
      (__attribute__((address_space(3))) unsigned int*)l, 16, 0, 0);
}

// ---------------------------------------------------------------------------
// Direct fp32 conv (d3: Cout=3+tanh). Optional CL hi/lo output.
// ---------------------------------------------------------------------------
template <int K, int S, int DIL>
__global__ __launch_bounds__(256) void conv2d_k(
    const float* __restrict__ x, const float* __restrict__ w,
    const float* __restrict__ bias, float* y, u16* clh, u16* cll, int WpO,
    int PoffO, long o_fstride, int N, int Cin, int Hin, int Win, int Cout,
    int Hout, int Wout, int pad, int act) {
  constexpr int TW = 8;
  constexpr int XL = (TW - 1) * S + (K - 1) * DIL + 1;
  int wq = (Wout + TW - 1) / TW;
  long gid = (long)blockIdx.x * 256 + threadIdx.x;
  long total = (long)N * Cout * Hout * wq;
  if (gid >= total) return;
  int xg = (int)(gid % wq);
  long r = gid / wq;
  int yo = (int)(r % Hout);
  r /= Hout;
  int oc = (int)(r % Cout);
  int n = (int)(r / Cout);

  float bv = bias[oc];
  float acc[TW];
#pragma unroll
  for (int j = 0; j < TW; ++j) acc[j] = bv;

  int xo0 = xg * TW;
  int xi0 = xo0 * S - pad;
  const float* xn = x + (long)n * Cin * Hin * Win;
  const float* wb = w + (long)oc * Cin * K * K;

  for (int ic = 0; ic < Cin; ++ic) {
    const float* xc = xn + (long)ic * Hin * Win;
    const float* wc = wb + ic * (K * K);
#pragma unroll
    for (int ky = 0; ky < K; ++ky) {
      int yi = yo * S - pad + ky * DIL;
      if ((unsigned)yi < (unsigned)Hin) {
        const float* row = xc + (long)yi * Win;
        float xr[XL];
#pragma unroll
        for (int i2 = 0; i2 < XL; ++i2) {
          int xi = xi0 + i2;
          xr[i2] = ((unsigned)xi < (unsigned)Win) ? row[xi] : 0.f;
        }
#pragma unroll
        for (int kx = 0; kx < K; ++kx) {
          float wv = wc[ky * K + kx];
#pragma unroll
          for (int j = 0; j < TW; ++j)
            acc[j] = fmaf(wv, xr[j * S + kx * DIL], acc[j]);
        }
      }
    }
  }

#pragma unroll
  for (int j = 0; j < TW; ++j) {
    if (xo0 + j < Wout) {
      float v = acc[j];
      if (act == ACT_LEAKY)
        v = v >= 0.f ? v : 0.2f * v;
      else if (act == ACT_TANH)
        v = tanhf(v);
      if (y) y[(((long)n * Cout + oc) * Hout + yo) * Wout + xo0 + j] = v;
      if (clh) {
        long off = (long)n * o_fstride +
                   ((long)(yo + PoffO) * WpO + (xo0 + j + PoffO)) * Cout + oc;
        splitw(v, &clh[off], &cll[off]);
      }
    }
  }
}

// ---------------------------------------------------------------------------
// enc0 (3->64, stride2) with oc-innermost lanes -> coalesced CL writes.
// ---------------------------------------------------------------------------
__global__ __launch_bounds__(256) void conv_enc0_cl(
    const float* __restrict__ x, const float* __restrict__ w,
    const float* __restrict__ bias, u16* __restrict__ clh,
    u16* __restrict__ cll) {
  __shared__ float ws[64][29];
  int t = threadIdx.x;
  for (int i = t; i < 64 * 27; i += 256) ws[i / 27][i % 27] = w[i];
  __syncthreads();
  int oc = t & 63;
  float bv = bias[oc];
  long s0 = (long)blockIdx.x * 32 + (t >> 6);
#pragma unroll
  for (int step = 0; step < 8; ++step) {
    long s = s0 + step * 4;
    int xo = (int)(s % 320);
    long r = s / 320;
    int yo = (int)(r % 60);
    int n = (int)(r / 60);
    float acc = bv;
    for (int ic = 0; ic < 3; ++ic) {
      const float* xp = x + ((long)n * 3 + ic) * 76800;
      const float* wp = ws[oc] + ic * 9;
#pragma unroll
      for (int ky = 0; ky < 3; ++ky) {
        int yi = yo * 2 - 1 + ky;
        if ((unsigned)yi < 120u) {
#pragma unroll
          for (int kx = 0; kx < 3; ++kx) {
            int xi = xo * 2 - 1 + kx;
            if ((unsigned)xi < 640u)
              acc = fmaf(wp[ky * 3 + kx], xp[yi * 640 + xi], acc);
          }
        }
      }
    }
    float v = acc >= 0.f ? acc : 0.2f * acc;
    long off = (long)n * 1327104 + ((long)(yo + 2) * 324 + (xo + 2)) * 64 + oc;
    splitw(v, &clh[off], &cll[off]);
  }
}

// ---------------------------------------------------------------------------
// LDS-staged MFMA implicit-GEMM conv, 2-term Ah*(Bh+Bl), 2-PHASE double
// buffer: STAGE(k+1) issued before compute(k); one barrier per K-step.
// ---------------------------------------------------------------------------
template <int WM, int WN>
__global__ __launch_bounds__(256) void conv_gemm_lds(
    const u16* __restrict__ Ah, const u16* __restrict__ Al,
    const u16* __restrict__ Bh, const u16* __restrict__ Bl,
    const float* __restrict__ bias, int Cin, int Cout, int Hout, int Wout,
    int Wp, int Poff, int S, int DIL, int pad, int taps, long a_fstride,
    int act, float* yout, long y_fstride, u16* Oh, u16* Ol, long o_fstride,
    int WpO, int PoffO, int useres) {
  constexpr int TM = WM * 64, TN = WN * 64;
  __shared__ u16 AsH[2 * TM * 32], BsH[2 * TN * 32], BsL[2 * TN * 32];
  int t = threadIdx.x;
  int lane = t & 63;
  int w = t >> 6;
  int wr = w / WN, wc = w % WN;
  int l15 = lane & 15, l16 = lane >> 4;
  int HW = Hout * Wout;
  int row0 = blockIdx.x * TM;
  int col0 = blockIdx.y * TN;
  const u16* Afh = Ah + (long)blockIdx.z * a_fstride;

  int rs = t >> 2;
  int cs = (t & 3) * 8;
  long abase[WM];
#pragma unroll
  for (int c = 0; c < WM; ++c) {
    int s = row0 + rs + 64 * c;
    if (s >= HW) s = HW - 1;
    int yo = s / Wout, xo = s - yo * Wout;
    int yb = yo * S - pad + Poff, xb = xo * S - pad + Poff;
    abase[c] = ((long)yb * Wp + xb) * Cin + cs;
  }
  long bbase[WN];
#pragma unroll
  for (int c = 0; c < WN; ++c)
    bbase[c] = (long)(col0 + rs + 64 * c) * Cin + cs;
  int ldst = w * 512;

  int nic = Cin >> 5;
  int NK = taps * nic;
  auto STAGE = [&](int kk, int buf) {
    int tap = kk / nic;
    int ic0 = (kk - tap * nic) << 5;
    int ky = tap / 3, kx = tap - ky * 3;
    long aoff = ((long)ky * DIL * Wp + kx * DIL) * Cin + ic0;
    long boff = (long)tap * Cout * Cin + ic0;
    u16* aB = AsH + buf * (TM * 32);
    u16* bhB = BsH + buf * (TN * 32);
    u16* blB = BsL + buf * (TN * 32);
#pragma unroll
    for (int c = 0; c < WM; ++c)
      gload16(Afh + abase[c] + aoff, aB + c * 2048 + ldst);
#pragma unroll
    for (int c = 0; c < WN; ++c) {
      gload16(Bh + bbase[c] + boff, bhB + c * 2048 + ldst);
      gload16(Bl + bbase[c] + boff, blB + c * 2048 + ldst);
    }
  };

  f32x4 acc[4][4];
#pragma unroll
  for (int m = 0; m < 4; ++m)
#pragma unroll
    for (int n = 0; n < 4; ++n) acc[m][n] = (f32x4){0.f, 0.f, 0.f, 0.f};

  STAGE(0, 0);
  __syncthreads();
  int cur = 0;
  for (int kk = 0; kk < NK; ++kk) {
    if (kk + 1 < NK) STAGE(kk + 1, cur ^ 1);
    const u16* aB = AsH + cur * (TM * 32);
    const u16* bhB = BsH + cur * (TN * 32);
    const u16* blB = BsL + cur * (TN * 32);
    bf16x8 ah[4];
#pragma unroll
    for (int m = 0; m < 4; ++m) {
      int rrow = wr * 64 + m * 16 + l15;
      ah[m] = *(const bf16x8*)(aB + rrow * 32 + l16 * 8);
    }
#pragma unroll
    for (int n = 0; n < 4; ++n) {
      int rcol = wc * 64 + n * 16 + l15;
      bf16x8 bh = *(const bf16x8*)(bhB + rcol * 32 + l16 * 8);
      bf16x8 bl = *(const bf16x8*)(blB + rcol * 32 + l16 * 8);
#pragma unroll
      for (int m = 0; m < 4; ++m) {
        acc[m][n] = MFMA(ah[m], bh, acc[m][n]);
        acc[m][n] = MFMA(ah[m], bl, acc[m][n]);
      }
    }
    __syncthreads();
    cur ^= 1;
  }

  float* yf = yout ? yout + (long)blockIdx.z * y_fstride : nullptr;
  u16* Ofh = Oh ? Oh + (long)blockIdx.z * o_fstride : nullptr;
  u16* Ofl = Ol ? Ol + (long)blockIdx.z * o_fstride : nullptr;
#pragma unroll
  for (int m = 0; m < 4; ++m) {
#pragma unroll
    for (int r = 0; r < 4; ++r) {
      int s = row0 + wr * 64 + m * 16 + l16 * 4 + r;
      if (s >= HW) continue;
      int yo = s / Wout, xo = s - yo * Wout;
      long clbase = 0;
      if (Ofh) clbase = ((long)(yo + PoffO) * WpO + (xo + PoffO)) * Cout;
#pragma unroll
      for (int n = 0; n < 4; ++n) {
        int oc = col0 + wc * 64 + n * 16 + l15;
        float v = acc[m][n][r] + bias[oc];
        if (act == ACT_LEAKY) v = v >= 0.f ? v : 0.2f * v;
        if (Ofh) {
          long off = clbase + oc;
          if (useres) v += bf2f(Ofh[off]) + bf2f(Ofl[off]);
          splitw(v, &Ofh[off], &Ofl[off]);
        }
        if (yf) yf[((long)oc * Hout + yo) * Wout + xo] = v;
      }
    }
  }
}

// ---------------------------------------------------------------------------
// Fused QKV 1x1 GEMM, 2-term, 2-phase dbuf. Tile 256x64, 4 waves.
// Token layout d = dm*64 + c. Q stores HI only.
// ---------------------------------------------------------------------------
__global__ __launch_bounds__(256) void qkv3_gemm_lds(
    const u16* __restrict__ Ah, const u16* __restrict__ Al, long a_fstride,
    int Wp, int Poff, const u16* __restrict__ qwh, const u16* __restrict__ qwl,
    const u16* __restrict__ kwh, const u16* __restrict__ kwl,
    const u16* __restrict__ vwh, const u16* __restrict__ vwl,
    const float* __restrict__ qbias, const float* __restrict__ kbias,
    const float* __restrict__ vbias, const int* __restrict__ nmap,
    const int* __restrict__ dmap, int ohow, int Dd, int pp, int NtokPad,
    float scale, u16* __restrict__ tqh, u16* __restrict__ tql,
    u16* __restrict__ tkh, u16* __restrict__ tkl, u16* __restrict__ tvh,
    u16* __restrict__ tvl) {
  __shared__ u16 AsH[2 * 256 * 32], BsH[2 * 64 * 32], BsL[2 * 64 * 32];
  int t = threadIdx.x;
  int lane = t & 63;
  int w = t >> 6;
  int l15 = lane & 15, l16 = lane >> 4;
  int row0 = blockIdx.x * 256;
  int frame = blockIdx.z;
  const u16* Afh = Ah + (long)frame * a_fstride;

  int rs = t >> 2;
  int cs = (t & 3) * 8;
  long abase[4];
#pragma unroll
  for (int c = 0; c < 4; ++c) {
    int s = row0 + rs + 64 * c;
    if (s >= 4800) s = 4799;
    int yo = s / 160, xo = s - yo * 160;
    abase[c] = ((long)(yo + Poff) * Wp + (xo + Poff)) * 256 + cs;
  }
  long bbase = (long)rs * 256 + cs;
  int ldst = w * 512;

  for (int mat = 0; mat < 3; ++mat) {
    const u16* Bh = mat == 0 ? qwh : mat == 1 ? kwh : vwh;
    const u16* Bl = mat == 0 ? qwl : mat == 1 ? kwl : vwl;
    const float* bias = mat == 0 ? qbias : mat == 1 ? kbias : vbias;
    u16* tH = mat == 0 ? tqh : mat == 1 ? tkh : tvh;
    u16* tL = mat == 0 ? tql : mat == 1 ? tkl : tvl;

    auto STAGE = [&](int kk, int buf) {
      int ic0 = kk << 5;
      u16* aB = AsH + buf * (256 * 32);
      u16* bhB = BsH + buf * (64 * 32);
      u16* blB = BsL + buf * (64 * 32);
#pragma unroll
      for (int c = 0; c < 4; ++c)
        gload16(Afh + abase[c] + ic0, aB + c * 2048 + ldst);
      gload16(Bh + bbase + ic0, bhB + ldst);
      gload16(Bl + bbase + ic0, blB + ldst);
    };

    f32x4 acc[4][4];
#pragma unroll
    for (int m = 0; m < 4; ++m)
#pragma unroll
      for (int n = 0; n < 4; ++n) acc[m][n] = (f32x4){0.f, 0.f, 0.f, 0.f};

    STAGE(0, 0);
    __syncthreads();
    int cur = 0;
    for (int kk = 0; kk < 8; ++kk) {
      if (kk + 1 < 8) STAGE(kk + 1, cur ^ 1);
      const u16* aB = AsH + cur * (256 * 32);
      const u16* bhB = BsH + cur * (64 * 32);
      const u16* blB = BsL + cur * (64 * 32);
      bf16x8 ah[4];
#pragma unroll
      for (int m = 0; m < 4; ++m) {
        int rrow = w * 64 + m * 16 + l15;
        ah[m] = *(const bf16x8*)(aB + rrow * 32 + l16 * 8);
      }
#pragma unroll
      for (int n = 0; n < 4; ++n) {
        int rcol = n * 16 + l15;
        bf16x8 bh = *(const bf16x8*)(bhB + rcol * 32 + l16 * 8);
        bf16x8 bl = *(const bf16x8*)(blB + rcol * 32 + l16 * 8);
#pragma unroll
        for (int m = 0; m < 4; ++m) {
          acc[m][n] = MFMA(ah[m], bh, acc[m][n]);
          acc[m][n] = MFMA(ah[m], bl, acc[m][n]);
        }
      }
      __syncthreads();
      cur ^= 1;
    }

#pragma unroll
    for (int m = 0; m < 4; ++m) {
#pragma unroll
      for (int r = 0; r < 4; ++r) {
        int s = row0 + w * 64 + m * 16 + l16 * 4 + r;
        if (s >= 4800) continue;
        int nm = nmap[s], dm = dmap[s];
        int ntok = frame * ohow + nm;
#pragma unroll
        for (int n = 0; n < 4; ++n) {
          int c = n * 16 + l15;
          float v = acc[m][n][r] + bias[c];
          if (mat == 0) v *= scale;
          int d = dm * 64 + c;
          long off = (mat == 2) ? ((long)d * NtokPad + ntok)
                                : ((long)ntok * Dd + d);
          u16 h = f2bf(v);
          tH[off] = h;
          if (mat != 0) tL[off] = f2bf(v - bf2f(h));
        }
      }
    }
  }
}

// ---------------------------------------------------------------------------
// QK GEMM, 2-term Qh*(Kh+Kl), 2-phase dbuf. Tile 128x128.
// ---------------------------------------------------------------------------
__global__ __launch_bounds__(256) void attn_gemm_lds(
    const u16* __restrict__ Ah, const u16* __restrict__ Al, int lda, int Mrows,
    const u16* __restrict__ Bh, const u16* __restrict__ Bl, int ldb,
    int Nclamp, int Kpart, int Nvalid, int mode, float* outf, int ldo,
    long partstride, u16* __restrict__ Oh, u16* __restrict__ Ol,
    const int* __restrict__ rowbase, const int* __restrict__ doff) {
  __shared__ u16 AsH[2 * 128 * 32], BsH[2 * 128 * 32], BsL[2 * 128 * 32];
  int t = threadIdx.x;
  int lane = t & 63;
  int w = t >> 6;
  int wc = w & 1, wr = w >> 1;
  int l15 = lane & 15, l16 = lane >> 4;
  int row0 = blockIdx.x * 128;
  int col0 = blockIdx.y * 128;
  int kbase = blockIdx.z * Kpart;
  if (outf) outf += (long)blockIdx.z * partstride;

  int rs = t >> 2;
  int cs = (t & 3) * 8;
  long abase[2], bbase[2];
#pragma unroll
  for (int c = 0; c < 2; ++c) {
    int sr = row0 + rs + 64 * c;
    if (sr >= Mrows) sr = Mrows - 1;
    abase[c] = (long)sr * lda + cs;
    int cc = col0 + rs + 64 * c;
    if (cc >= Nclamp) cc = Nclamp - 1;
    bbase[c] = (long)cc * ldb + cs;
  }
  int ldst = w * 512;

  int NK = Kpart >> 5;
  auto STAGE = [&](int kk, int buf) {
    long k = kbase + ((long)kk << 5);
    u16* aB = AsH + buf * (128 * 32);
    u16* bhB = BsH + buf * (128 * 32);
    u16* blB = BsL + buf * (128 * 32);
#pragma unroll
    for (int c = 0; c < 2; ++c) {
      gload16(Ah + abase[c] + k, aB + c * 2048 + ldst);
      gload16(Bh + bbase[c] + k, bhB + c * 2048 + ldst);
      gload16(Bl + bbase[c] + k, blB + c * 2048 + ldst);
    }
  };

  f32x4 acc[4][4];
#pragma unroll
  for (int m = 0; m < 4; ++m)
#pragma unroll
    for (int n = 0; n < 4; ++n) acc[m][n] = (f32x4){0.f, 0.f, 0.f, 0.f};

  STAGE(0, 0);
  __syncthreads();
  int cur = 0;
  for (int kk = 0; kk < NK; ++kk) {
    if (kk + 1 < NK) STAGE(kk + 1, cur ^ 1);
    const u16* aB = AsH + cur * (128 * 32);
    const u16* bhB = BsH + cur * (128 * 32);
    const u16* blB = BsL + cur * (128 * 32);
    bf16x8 ah[4];
#pragma unroll
    for (int m = 0; m < 4; ++m) {
      int rrow = wr * 64 + m * 16 + l15;
      ah[m] = *(const bf16x8*)(aB + rrow * 32 + l16 * 8);
    }
#pragma unroll
    for (int n = 0; n < 4; ++n) {
      int rcol = wc * 64 + n * 16 + l15;
      bf16x8 bh = *(const bf16x8*)(bhB + rcol * 32 + l16 * 8);
      bf16x8 bl = *(const bf16x8*)(blB + rcol * 32 + l16 * 8);
#pragma unroll
      for (int m = 0; m < 4; ++m) {
        acc[m][n] = MFMA(ah[m], bh, acc[m][n]);
        acc[m][n] = MFMA(ah[m], bl, acc[m][n]);
      }
    }
    __syncthreads();
    cur ^= 1;
  }

#pragma unroll
  for (int m = 0; m < 4; ++m) {
#pragma unroll
    for (int r = 0; r < 4; ++r) {
      int sr = row0 + wr * 64 + m * 16 + l16 * 4 + r;
      if (sr >= Mrows) continue;
#pragma unroll
      for (int n = 0; n < 4; ++n) {
        int c = col0 + wc * 64 + n * 16 + l15;
        if (c >= Nvalid) continue;
        float v = acc[m][n][r];
        if (mode == 0) {
          outf[(long)sr * ldo + c] = v;
        } else {
          long off = (long)rowbase[sr] + doff[c];
          splitw(v, &Oh[off], &Ol[off]);
        }
      }
    }
  }
}

// ---------------------------------------------------------------------------
// PV GEMM, 2-term Ph*(Vh+Vl), 2-phase dbuf. A = fp32 P rows (hi on the fly).
// ---------------------------------------------------------------------------
__global__ __launch_bounds__(256) void attn_pv_lds(
    const float* __restrict__ P, int lda, int Mrows,
    const u16* __restrict__ Bh, const u16* __restrict__ Bl, int ldb,
    int Nclamp, int Kpart, int Nvalid, int mode, float* outf, int ldo,
    long partstride, u16* __restrict__ Oh, u16* __restrict__ Ol,
    const int* __restrict__ rowbase, const int* __restrict__ doff) {
  __shared__ float Asf[2 * 128 * 32];
  __shared__ u16 BsH[2 * 128 * 32], BsL[2 * 128 * 32];
  int t = threadIdx.x;
  int lane = t & 63;
  int w = t >> 6;
  int wc = w & 1, wr = w >> 1;
  int l15 = lane & 15, l16 = lane >> 4;
  int row0 = blockIdx.x * 128;
  int col0 = blockIdx.y * 128;
  int kbase = blockIdx.z * Kpart;
  if (outf) outf += (long)blockIdx.z * partstride;

  int arow = t >> 3;
  int acol = (t & 7) * 4;
  long abase[4];
#pragma unroll
  for (int j = 0; j < 4; ++j) {
    int r = row0 + arow + 32 * j;
    if (r >= Mrows) r = Mrows - 1;
    abase[j] = (long)r * lda + acol;
  }
  int rs = t >> 2;
  int cs = (t & 3) * 8;
  long bbase[2];
#pragma unroll
  for (int c = 0; c < 2; ++c) {
    int cc = col0 + rs + 64 * c;
    if (cc >= Nclamp) cc = Nclamp - 1;
    bbase[c] = (long)cc * ldb + cs;
  }
  int ldst = w * 512;

  int NK = Kpart >> 5;
  auto STAGE = [&](int kk, int buf) {
    long k = kbase + ((long)kk << 5);
    float* aB = Asf + buf * (128 * 32);
    u16* bhB = BsH + buf * (128 * 32);
    u16* blB = BsL + buf * (128 * 32);
#pragma unroll
    for (int j = 0; j < 4; ++j)
      gload16(P + abase[j] + k, aB + (w * 64 + 256 * j) * 4);
#pragma unroll
    for (int c = 0; c < 2; ++c) {
      gload16(Bh + bbase[c] + k, bhB + c * 2048 + ldst);
      gload16(Bl + bbase[c] + k, blB + c * 2048 + ldst);
    }
  };

  f32x4 acc[4][4];
#pragma unroll
  for (int m = 0; m < 4; ++m)
#pragma unroll
    for (int n = 0; n < 4; ++n) acc[m][n] = (f32x4){0.f, 0.f, 0.f, 0.f};

  STAGE(0, 0);
  __syncthreads();
  int cur = 0;
  for (int kk = 0; kk < NK; ++kk) {
    if (kk + 1 < NK) STAGE(kk + 1, cur ^ 1);
    const float* aB = Asf + cur * (128 * 32);
    const u16* bhB = BsH + cur * (128 * 32);
    const u16* blB = BsL + cur * (128 * 32);
    bf16x8 ah[4];
#pragma unroll
    for (int m = 0; m < 4; ++m) {
      int rrow = wr * 64 + m * 16 + l15;
      const float* ap = aB + rrow * 32 + l16 * 8;
      f32x4 p0 = *(const f32x4*)(ap);
      f32x4 p1 = *(const f32x4*)(ap + 4);
#pragma unroll
      for (int e = 0; e < 4; ++e) {
        ah[m][e] = (short)f2bf(p0[e]);
        ah[m][4 + e] = (short)f2bf(p1[e]);
      }
    }
#pragma unroll
    for (int n = 0; n < 4; ++n) {
      int rcol = wc * 64 + n * 16 + l15;
      bf16x8 bh = *(const bf16x8*)(bhB + rcol * 32 + l16 * 8);
      bf16x8 bl = *(const bf16x8*)(blB + rcol * 32 + l16 * 8);
#pragma unroll
      for (int m = 0; m < 4; ++m) {
        acc[m][n] = MFMA(ah[m], bh, acc[m][n]);
        acc[m][n] = MFMA(ah[m], bl, acc[m][n]);
      }
    }
    __syncthreads();
    cur ^= 1;
  }

#pragma unroll
  for (int m = 0; m < 4; ++m) {
#pragma unroll
    for (int r = 0; r < 4; ++r) {
      int sr = row0 + wr * 64 + m * 16 + l16 * 4 + r;
      if (sr >= Mrows) continue;
#pragma unroll
      for (int n = 0; n < 4; ++n) {
        int c = col0 + wc * 64 + n * 16 + l15;
        if (c >= Nvalid) continue;
        float v = acc[m][n][r];
        if (mode == 0) {
          outf[(long)sr * ldo + c] = v;
        } else {
          long off = (long)rowbase[sr] + doff[c];
          splitw(v, &Oh[off], &Ol[off]);
        }
      }
    }
  }
}

// ---------------------------------------------------------------------------
__global__ __launch_bounds__(256) void reduce_scatter(
    const float* __restrict__ parts, int nparts, long pstride, int rows, int N,
    int mode, float* outf, u16* __restrict__ Oh, u16* __restrict__ Ol,
    const int* __restrict__ rowbase, const int* __restrict__ doff) {
  long gid = (long)blockIdx.x * 256 + threadIdx.x;
  long tot = (long)rows * N;
  if (gid >= tot) return;
  float s = 0.f;
  for (int p = 0; p < nparts; ++p) s += parts[p * pstride + gid];
  if (mode == 0) {
    outf[gid] = s;
  } else {
    int r = (int)(gid / N), c = (int)(gid % N);
    long off = (long)rowbase[r] + doff[c];
    splitw(s, &Oh[off], &Ol[off]);
  }
}

// ---------------------------------------------------------------------------
__global__ __launch_bounds__(256) void softmax_ip(float* __restrict__ S,
                                                  int Ntok, int NtokPad) {
  int row = blockIdx.x;
  float* p = S + (long)row * NtokPad;
  __shared__ float red[256];
  int t = threadIdx.x;
  float m = -1e30f;
  for (int i = t; i < Ntok; i += 256) m = fmaxf(m, p[i]);
  red[t] = m;
  __syncthreads();
  for (int s = 128; s > 0; s >>= 1) {
    if (t < s) red[t] = fmaxf(red[t], red[t + s]);
    __syncthreads();
  }
  m = red[0];
  __syncthreads();
  float sum = 0.f;
  for (int i = t; i < Ntok; i += 256) sum += __expf(p[i] - m);
  red[t] = sum;
  __syncthreads();
  for (int s = 128; s > 0; s >>= 1) {
    if (t < s) red[t] += red[t + s];
    __syncthreads();
  }
  float inv = 1.f / red[0];
  __syncthreads();
  for (int i = t; i < Ntok; i += 256) p[i] = __expf(p[i] - m) * inv;
  for (int i = Ntok + t; i < NtokPad; i += 256) p[i] = 0.f;
}

// ---------------------------------------------------------------------------
__global__ __launch_bounds__(256) void wt_build(const float* __restrict__ w,
                                                int Cout, int Cin, int taps,
                                                u16* __restrict__ Wh,
                                                u16* __restrict__ Wl) {
  long gid = (long)blockIdx.x * 256 + threadIdx.x;
  long tot = (long)taps * Cout * Cin;
  if (gid >= tot) return;
  int ic = (int)(gid % Cin);
  long r = gid / Cin;
  int oc = (int)(r % Cout);
  int tap = (int)(r / Cout);
  float v = w[((long)oc * Cin + ic) * taps + tap];
  splitw(v, &Wh[gid], &Wl[gid]);
}

// build to/ff1/ff2 weight splits (256x256x9 each) in one dispatch
__global__ __launch_bounds__(256) void wt3_build(const float* __restrict__ w0,
                                                 const float* __restrict__ w1,
                                                 const float* __restrict__ w2,
                                                 u16* __restrict__ base) {
  long gid = (long)blockIdx.x * 256 + threadIdx.x;
  if (gid >= 3L * 589824) return;
  int mat = (int)(gid / 589824);
  int idx = (int)(gid - (long)mat * 589824);
  const float* w = mat == 0 ? w0 : mat == 1 ? w1 : w2;
  int ic = idx & 255;
  int r = idx >> 8;
  int oc = r & 255;
  int tap = r >> 8;
  float v = w[((long)oc * 256 + ic) * 9 + tap];
  u16* dst = base + (long)mat * 1179648;
  splitw(v, &dst[idx], &dst[589824 + idx]);
}

// fused q/k/v 1x1 weight split build, ALL 4 groups in one dispatch.
__global__ __launch_bounds__(256) void wtqkv_build_all(
    const float* __restrict__ wq, const float* __restrict__ wk,
    const float* __restrict__ wv, u16* __restrict__ qh, u16* __restrict__ ql,
    u16* __restrict__ kh, u16* __restrict__ kl, u16* __restrict__ vh,
    u16* __restrict__ vl) {
  int gid = blockIdx.x * 256 + threadIdx.x;
  if (gid >= 4 * 64 * 256) return;
  int ic = gid & 255;
  int c = (gid >> 8) & 63;
  int g = gid >> 14;
  long src = (long)(g * 64 + c) * 256 + ic;
  splitw(wq[src], &qh[gid], &ql[gid]);
  splitw(wk[src], &kh[gid], &kl[gid]);
  splitw(wv[src], &vh[gid], &vl[gid]);
}

// ---------------------------------------------------------------------------
__global__ __launch_bounds__(256) void maps_build(int ph, int pw, int ow,
                                                  int* __restrict__ nmap,
                                                  int* __restrict__ dmap) {
  int s = blockIdx.x * 256 + threadIdx.x;
  if (s >= 4800) return;
  int y = s / 160, x = s - y * 160;
  int i = y / ph, yy = y - i * ph;
  int j = x / pw, xx = x - j * pw;
  nmap[s] = i * ow + j;
  dmap[s] = yy * pw + xx;
}

// d = dm*64 + ch (channels innermost). doff[d] contiguous in ch.
__global__ __launch_bounds__(256) void luts_build(int ph, int pw, int ohow,
                                                  int ow, int pp, int Ntok,
                                                  int Dd, int gbase,
                                                  int* __restrict__ rowbase,
                                                  int* __restrict__ doff) {
  int gid = blockIdx.x * 256 + threadIdx.x;
  if (gid < Ntok) {
    int tt = gid / ohow, rem = gid - tt * ohow;
    int i = rem / ow, j = rem - i * ow;
    rowbase[gid] =
        tt * (32 * 162 * 256) + ((i * ph + 1) * 162 + (j * pw + 1)) * 256;
  }
  if (gid < Dd) {
    int ch = gid & 63;
    int dm = gid >> 6;
    int yy = dm / pw, xx = dm - yy * pw;
    doff[gid] = (yy * 162 + xx) * 256 + gbase + ch;
  }
}

// ---------------------------------------------------------------------------
// Bilinear x2 upsample (align_corners) CL hi/lo -> CL hi/lo, full padded
// write. blockIdx.z = frame; s_fs/o_fs are per-frame element strides.
// ---------------------------------------------------------------------------
__global__ __launch_bounds__(256) void up_cl2cl_pad(
    const u16* __restrict__ sh, const u16* __restrict__ sl,
    u16* __restrict__ oh, u16* __restrict__ ol, long s_fs, long o_fs, int C,
    int H, int W, int Wps, int Poffs, int Hp, int Wpo, int Poffo) {
  sh += (long)blockIdx.z * s_fs;
  sl += (long)blockIdx.z * s_fs;
  oh += (long)blockIdx.z * o_fs;
  ol += (long)blockIdx.z * o_fs;
  int Ho = 2 * H, Wo = 2 * W;
  long tot = (long)Hp * Wpo * C;
  long gid = (long)blockIdx.x * 256 + threadIdx.x;
  if (gid >= tot) return;
  int c = (int)(gid % C);
  long r = gid / C;
  int xp = (int)(r % Wpo);
  int yp = (int)(r / Wpo);
  int x = xp - Poffo, y = yp - Poffo;
  float v = 0.f;
  if ((unsigned)x < (unsigned)Wo && (unsigned)y < (unsigned)Ho) {
    float fy = (float)(y * (H - 1)) / (float)(Ho - 1);
    float fx = (float)(x * (W - 1)) / (float)(Wo - 1);
    int y0 = (int)fy, x0 = (int)fx;
    int y1 = min(y0 + 1, H - 1), x1 = min(x0 + 1, W - 1);
    float wy = fy - y0, wx = fx - x0;
    auto rd = [&](int cy, int cx) {
      long o = ((long)(cy + Poffs) * Wps + (cx + Poffs)) * C + c;
      return bf2f(sh[o]) + bf2f(sl[o]);
    };
    float r0 = rd(y0, x0) * (1.f - wx) + rd(y0, x1) * wx;
    float r1 = rd(y1, x0) * (1.f - wx) + rd(y1, x1) * wx;
    v = r0 * (1.f - wy) + r1 * wy;
  }
  splitw(v, &oh[gid], &ol[gid]);
}

// ---------------------------------------------------------------------------
extern "C" void kernel_launch(void* const* d_in, const int* in_sizes, int n_in,
                              void* d_out, int out_size, void* d_ws,
                              size_t ws_size, hipStream_t stream) {
  const float* input = (const float*)d_in[0];
  const float* enc_w0 = (const float*)d_in[1];
  const float* enc_b0 = (const float*)d_in[2];
  const float* enc_w1 = (const float*)d_in[3];
  const float* enc_b1 = (const float*)d_in[4];
  const float* enc_w2 = (const float*)d_in[5];
  const float* enc_b2 = (const float*)d_in[6];
  const float* enc_w3 = (const float*)d_in[7];
  const float* enc_b3 = (const float*)d_in[8];
  const float* tq_w = (const float*)d_in[9];
  const float* tq_b = (const float*)d_in[10];
  const float* tk_w = (const float*)d_in[11];
  const float* tk_b = (const float*)d_in[12];
  const float* tv_w = (const float*)d_in[13];
  const float* tv_b = (const float*)d_in[14];
  const float* to_w = (const float*)d_in[15];
  const float* to_b = (const float*)d_in[16];
  const float* tf1_w = (const float*)d_in[17];
  const float* tf1_b = (const float*)d_in[18];
  const float* tf2_w = (const float*)d_in[19];
  const float* tf2_b = (const float*)d_in[20];
  const float* d0_w = (const float*)d_in[21];
  const float* d0_b = (const float*)d_in[22];
  const float* d1_w = (const float*)d_in[23];
  const float* d1_b = (const float*)d_in[24];
  const float* d2_w = (const float*)d_in[25];
  const float* d2_b = (const float*)d_in[26];
  const float* d3_w = (const float*)d_in[27];
  const float* d3_b = (const float*)d_in[28];
  float* out = (float*)d_out;

  // -------- workspace layout --------
  unsigned char* wsb = (unsigned char*)d_ws;
  size_t off = 0;
  auto alloc = [&](size_t bytes) {
    void* p = wsb + off;
    off = (off + bytes + 255) & ~(size_t)255;
    return p;
  };
  const long XCL_E = 22839296L;   // 16*34*164*256
  const long XCL2_E = 21233664L;  // 16*32*162*256
  const long QT_E = 4915200L;
  const long VT_E = 5111808L;
  u16* XCLh = (u16*)alloc(XCL_E * 2);
  u16* XCLl = (u16*)alloc(XCL_E * 2);
  u16* XCL2h = (u16*)alloc(XCL2_E * 2);
  u16* XCL2l = (u16*)alloc(XCL2_E * 2);
  u16* qth = (u16*)alloc(QT_E * 2);
  u16* qtl = (u16*)alloc(QT_E * 2);
  u16* kth = (u16*)alloc(QT_E * 2);
  u16* ktl = (u16*)alloc(QT_E * 2);
  u16* vth = (u16*)alloc(VT_E * 2);
  u16* vtl = (u16*)alloc(VT_E * 2);
  int* nmapA = (int*)alloc(4 * 4800 * 4);
  int* dmapA = (int*)alloc(4 * 4800 * 4);
  int* rowbaseA = (int*)alloc(7120 * 4);
  int* doffA = (int*)alloc(93248 * 4);
  u16* qwh = (u16*)alloc(65536 * 2);
  u16* qwl = (u16*)alloc(65536 * 2);
  u16* kwh = (u16*)alloc(65536 * 2);
  u16* kwl = (u16*)alloc(65536 * 2);
  u16* vwh = (u16*)alloc(65536 * 2);
  u16* vwl = (u16*)alloc(65536 * 2);
  size_t fixed_end = off;
  size_t avail = ws_size > fixed_end ? ws_size - fixed_end : 0;
  size_t SCB = avail > 4096 ? avail - 4096 : 0;
  if (SCB > 104857600UL) SCB = 104857600UL;
  float* scores = (float*)alloc(SCB);
  size_t need = off;
  if (ws_size < need) return;  // fail loud, not crash
  long SCAPf = (long)(SCB / 4);
  if (SCAPf < 1800000) return;

  // encoder weight splits + trunk wt3 region overlay the scores region
  u16* Wth = (u16*)scores;
  u16* Wtl = Wth + 589824;
  u16* W3 = (u16*)scores;

  // ---- decoder buffers: overlay XCL2+token+scores region ----
  unsigned char* decbase = (unsigned char*)XCL2h;
  u16* dec0inH = (u16*)(decbase + 0);
  u16* dec0inL = (u16*)(decbase + 40886272);
  u16* dec0outH = (u16*)(decbase + 81772544);
  u16* dec0outL = (u16*)(decbase + 102215680);
  u16* dec1outH = (u16*)(decbase + 122658816);
  u16* dec1outL = (u16*)(decbase + 132880384);
  u16* dec2inH = (u16*)(decbase + 0);
  u16* dec2inL = (u16*)(decbase + 20050944);
  float* dec2out = (float*)(decbase + 40101888);
  u16* Wd0h = (u16*)(decbase + 143101952);
  u16* Wd0l = Wd0h + 294912;
  u16* W1h = Wd0l + 294912;
  u16* W1l = W1h + 73728;
  u16* W2h = W1l + 73728;
  u16* W2l = W2h + 36864;
  const long D0IN_FS = 5110784, D0OUT_FS = 2555392, D1OUT_FS = 1277696;
  const long D2IN_FS = 5012736, D2OUT_FS = 4915200;

  const long FS_TR = 1427456;  // 34*164*256
  const long FS_T2 = 1327104;  // 32*162*256 == 64*324*64
  const long FS_E2 = 713728;   // 34*164*128

  static const int PWa[4] = {80, 32, 10, 5};
  static const int PHa[4] = {15, 6, 5, 3};
  static const int rbOff[4] = {0, 64, 464, 2000};
  static const int doOff[4] = {0, 76800, 89088, 92288};

  // -------- encoder --------
  hipMemsetAsync(XCLh, 0, XCL_E * 2, stream);
  hipMemsetAsync(XCLl, 0, XCL_E * 2, stream);
  hipMemsetAsync(XCL2h, 0, XCL2_E * 2, stream);
  hipMemsetAsync(XCL2l, 0, XCL2_E * 2, stream);
  hipMemsetAsync(vth, 0, VT_E * 2, stream);
  hipMemsetAsync(vtl, 0, VT_E * 2, stream);
  conv_enc0_cl<<<9600, 256, 0, stream>>>(input, enc_w0, enc_b0, XCL2h, XCL2l);
  {  // enc1
    wt_build<<<cdivu(9L * 64 * 64, 256), 256, 0, stream>>>(enc_w1, 64, 64, 9,
                                                           Wth, Wtl);
    conv_gemm_lds<4, 1><<<dim3(75, 1, 16), 256, 0, stream>>>(
        XCL2h, XCL2l, Wth, Wtl, enc_b1, 64, 64, 60, 320, 324, 2, 1, 1, 1, 9,
        FS_T2, ACT_LEAKY, nullptr, 0, XCLh, XCLl, FS_T2, 324, 2, 0);
  }
  hipMemsetAsync(XCL2h, 0, XCL2_E * 2, stream);
  hipMemsetAsync(XCL2l, 0, XCL2_E * 2, stream);
  {  // enc2
    wt_build<<<cdivu(9L * 128 * 64, 256), 256, 0, stream>>>(enc_w2, 128, 64, 9,
                                                            Wth, Wtl);
    conv_gemm_lds<2, 2><<<dim3(38, 1, 16), 256, 0, stream>>>(
        XCLh, XCLl, Wth, Wtl, enc_b2, 64, 128, 30, 160, 324, 2, 2, 1, 1, 9,
        FS_T2, ACT_LEAKY, nullptr, 0, XCL2h, XCL2l, FS_E2, 164, 2, 0);
  }
  hipMemsetAsync(XCLh, 0, XCL_E * 2, stream);
  hipMemsetAsync(XCLl, 0, XCL_E * 2, stream);
  {  // enc3
    wt_build<<<cdivu(9L * 256 * 128, 256), 256, 0, stream>>>(enc_w3, 256, 128,
                                                             9, Wth, Wtl);
    conv_gemm_lds<2, 2><<<dim3(38, 2, 16), 256, 0, stream>>>(
        XCL2h, XCL2l, Wth, Wtl, enc_b3, 128, 256, 30, 160, 164, 2, 1, 1, 1, 9,
        FS_E2, ACT_LEAKY, nullptr, 0, XCLh, XCLl, FS_TR, 164, 2, 0);
  }
  hipMemsetAsync(XCL2h, 0, XCL2_E * 2, stream);
  hipMemsetAsync(XCL2l, 0, XCL2_E * 2, stream);

  // -------- token maps / scatter LUTs --------
  for (int g = 0; g < 4; ++g) {
    int ph = PHa[g], pw = PWa[g];
    int ohh = 30 / ph, oww = 160 / pw;
    int Ntok = 16 * ohh * oww, Dd = 64 * ph * pw, pp = ph * pw;
    maps_build<<<19, 256, 0, stream>>>(ph, pw, oww, nmapA + g * 4800,
                                       dmapA + g * 4800);
    int mx = Ntok > Dd ? Ntok : Dd;
    luts_build<<<cdivu(mx, 256), 256, 0, stream>>>(
        ph, pw, ohh * oww, oww, pp, Ntok, Dd, g * 64, rowbaseA + rbOff[g],
        doffA + doOff[g]);
  }

  // -------- transformer stack --------
  for (int l = 0; l < 8; ++l) {
    wtqkv_build_all<<<256, 256, 0, stream>>>(
        tq_w + (long)l * 65536, tk_w + (long)l * 65536,
        tv_w + (long)l * 65536, qwh, qwl, kwh, kwl, vwh, vwl);

    for (int g = 0; g < 4; ++g) {
      int ph = PHa[g], pw = PWa[g];
      int ohh = 30 / ph, oww = 160 / pw;
      int ohow = ohh * oww;
      int Ntok = 16 * ohow, Dd = 64 * ph * pw, pp = ph * pw;
      int NtokPad = (Ntok + 31) & ~31;
      float scale = 1.0f / sqrtf((float)Dd);
      const int* nmap = nmapA + g * 4800;
      const int* dmap = dmapA + g * 4800;
      const int* rowbase = rowbaseA + rbOff[g];
      const int* doffp = doffA + doOff[g];

      qkv3_gemm_lds<<<dim3(19, 1, 16), 256, 0, stream>>>(
          XCLh, XCLl, FS_TR, 164, 2, qwh + g * 16384, qwl + g * 16384,
          kwh + g * 16384, kwl + g * 16384, vwh + g * 16384, vwl + g * 16384,
          tq_b + l * 256 + g * 64, tk_b + l * 256 + g * 64,
          tv_b + l * 256 + g * 64, nmap, dmap, ohow, Dd, pp, NtokPad, scale,
          qth, qtl, kth, ktl, vth, vtl);

      if (g == 0) {
        float* scoresR = scores + 131072;
        attn_gemm_lds<<<dim3(1, 1, 32), 256, 0, stream>>>(
            qth, qtl, Dd, 64, kth, ktl, Dd, 64, 2400, 64, 0, scores, 64, 4096,
            nullptr, nullptr, nullptr, nullptr);
        reduce_scatter<<<16, 256, 0, stream>>>(scores, 32, 4096, 64, 64, 0,
                                               scoresR, nullptr, nullptr,
                                               nullptr, nullptr);
        softmax_ip<<<64, 256, 0, stream>>>(scoresR, 64, 64);
        attn_pv_lds<<<dim3(1, 600, 1), 256, 0, stream>>>(
            scoresR, 64, 64, vth, vtl, 64, Dd, 64, Dd, 1, nullptr, 0, 0,
            XCL2h, XCL2l, rowbase, doffp);
      } else {
        long denom = (long)NtokPad + (g == 3 ? 3840 : 0);
        long cap = (SCAPf / denom) & ~127L;
        int chunk = (int)(cap < 128 ? 128 : cap);
        if (chunk > Ntok) chunk = Ntok;
        float* partials = scores + (long)chunk * NtokPad;
        for (int r0 = 0; r0 < Ntok; r0 += chunk) {
          int rows = Ntok - r0 < chunk ? Ntok - r0 : chunk;
          attn_gemm_lds<<<dim3(cdivu(rows, 128), cdivu(Ntok, 128), 1), 256, 0,
                          stream>>>(qth + (long)r0 * Dd, qtl + (long)r0 * Dd,
                                    Dd, rows, kth, ktl, Dd, Ntok, Dd, Ntok, 0,
                                    scores, NtokPad, 0, nullptr, nullptr,
                                    nullptr, nullptr);
          softmax_ip<<<rows, 256, 0, stream>>>(scores, Ntok, NtokPad);
          if (g == 3) {
            attn_pv_lds<<<dim3(cdivu(rows, 128), 8, 4), 256, 0, stream>>>(
                scores, NtokPad, rows, vth, vtl, NtokPad, Dd, 1280, Dd, 0,
                partials, 960, (long)rows * 960, nullptr, nullptr, nullptr,
                nullptr);
            reduce_scatter<<<cdivu((long)rows * 960, 256), 256, 0, stream>>>(
                partials, 4, (long)rows * 960, rows, 960, 1, nullptr, XCL2h,
                XCL2l, rowbase + r0, doffp);
          } else {
            attn_pv_lds<<<dim3(cdivu(rows, 128), Dd / 128, 1), 256, 0,
                          stream>>>(scores, NtokPad, rows, vth, vtl, NtokPad,
                                    Dd, NtokPad, Dd, 1, nullptr, 0, 0, XCL2h,
                                    XCL2l, rowbase + r0, doffp);
          }
        }
      }
    }

    wt3_build<<<6912, 256, 0, stream>>>(to_w + (long)l * 589824,
                                        tf1_w + (long)l * 589824,
                                        tf2_w + (long)l * 589824, W3);
    conv_gemm_lds<2, 2><<<dim3(38, 2, 16), 256, 0, stream>>>(
        XCL2h, XCL2l, W3, W3 + 589824, to_b + l * 256, 256, 256, 30, 160, 162,
        1, 1, 1, 1, 9, FS_T2, ACT_LEAKY, nullptr, 0, XCLh, XCLl, FS_TR, 164, 2,
        1);
    conv_gemm_lds<2, 2><<<dim3(38, 2, 16), 256, 0, stream>>>(
        XCLh, XCLl, W3 + 1179648, W3 + 1769472, tf1_b + l * 256, 256, 256, 30,
        160, 164, 2, 1, 2, 2, 9, FS_TR, ACT_LEAKY, nullptr, 0, XCL2h, XCL2l,
        FS_T2, 162, 1, 0);
    conv_gemm_lds<2, 2><<<dim3(38, 2, 16), 256, 0, stream>>>(
        XCL2h, XCL2l, W3 + 2359296, W3 + 2949120, tf2_b + l * 256, 256, 256,
        30, 160, 162, 1, 1, 1, 1, 9, FS_T2, ACT_LEAKY, nullptr, 0, XCLh, XCLl,
        FS_TR, 164, 2, 1);
  }

  // -------- decoder: 4-frame front half, 2-frame back half --------
  hipMemsetAsync(decbase, 0, 144723968, stream);
  wt_build<<<cdivu(9L * 128 * 256, 256), 256, 0, stream>>>(d0_w, 128, 256, 9,
                                                           Wd0h, Wd0l);
  wt_build<<<cdivu(9L * 64 * 128, 256), 256, 0, stream>>>(d1_w, 64, 128, 9,
                                                          W1h, W1l);
  wt_build<<<cdivu(9L * 64 * 64, 256), 256, 0, stream>>>(d2_w, 64, 64, 9, W2h,
                                                         W2l);
  for (int f = 0; f < 16; f += 4) {
    up_cl2cl_pad<<<dim3(cdivu(62L * 322 * 256, 256), 1, 4), 256, 0, stream>>>(
        XCLh + (long)f * FS_TR, XCLl + (long)f * FS_TR, dec0inH, dec0inL,
        FS_TR, D0IN_FS, 256, 30, 160, 164, 2, 62, 322, 1);
    conv_gemm_lds<2, 2><<<dim3(150, 1, 4), 256, 0, stream>>>(
        dec0inH, dec0inL, Wd0h, Wd0l, d0_b, 256, 128, 60, 320, 322, 1, 1, 1, 1,
        9, D0IN_FS, ACT_LEAKY, nullptr, 0, dec0outH, dec0outL, D0OUT_FS, 322,
        1, 0);
    conv_gemm_lds<4, 1><<<dim3(75, 1, 4), 256, 0, stream>>>(
        dec0outH, dec0outL, W1h, W1l, d1_b, 128, 64, 60, 320, 322, 1, 1, 1, 1,
        9, D0OUT_FS, ACT_LEAKY, nullptr, 0, dec1outH, dec1outL, D1OUT_FS, 322,
        1, 0);
    for (int ff = 0; ff < 4; ff += 2) {
      up_cl2cl_pad<<<dim3(cdivu(122L * 642 * 64, 256), 1, 2), 256, 0,
                     stream>>>(dec1outH + (long)ff * D1OUT_FS,
                               dec1outL + (long)ff * D1OUT_FS, dec2inH,
                               dec2inL, D1OUT_FS, D2IN_FS, 64, 60, 320, 322, 1,
                               122, 642, 1);
      conv_gemm_lds<4, 1><<<dim3(300, 1, 2), 256, 0, stream>>>(
          dec2inH, dec2inL, W2h, W2l, d2_b, 64, 64, 120, 640, 642, 1, 1, 1, 1,
          9, D2IN_FS, ACT_LEAKY, dec2out, D2OUT_FS, nullptr, nullptr, 0, 0, 0,
          0);
      long tot = 2L * 3 * 120 * 80;
      conv2d_k<3, 1, 1><<<cdivu(tot, 256), 256, 0, stream>>>(
          dec2out, d3_w, d3_b, out + (long)(f + ff) * 230400, nullptr, nullptr,
          0, 0, 0, 2, 64, 120, 640, 3, 120, 640, 1, ACT_TANH);
    }
  }
}

// Round 16
// 26334.900 us; speedup vs baseline: 38.9485x; 1.0098x over previous
//
#include <hip/hip_runtime.h>
#include <hip/hip_bf16.h>
#include <math.h>

#define ACT_NONE 0
#define ACT_LEAKY 1
#define ACT_TANH 2

typedef __attribute__((ext_vector_type(8))) short bf16x8;
typedef __attribute__((ext_vector_type(4))) float f32x4;
typedef unsigned short u16;

#define MFMA(a, b, c) __builtin_amdgcn_mfma_f32_16x16x32_bf16((bf16x8)(a), (bf16x8)(b), (c), 0, 0, 0)

static inline unsigned cdivu(long a, long b) { return (unsigned)((a + b - 1) / b); }

__device__ __forceinline__ u16 f2bf(float x) {
  union { __hip_bfloat16 h; u16 u; } cv;
  cv.h = __float2bfloat16(x);
  return cv.u;
}
__device__ __forceinline__ float bf2f(u16 b) {
  union { u16 u; __hip_bfloat16 h; } cv;
  cv.u = b;
  return __bfloat162float(cv.h);
}
__device__ __forceinline__ void splitw(float v, u16* ph, u16* pl) {
  u16 h = f2bf(v);
  *ph = h;
  *pl = f2bf(v - bf2f(h));
}
// async global->LDS, 16B per lane; dest must be wave-uniform base (+lane*16)
__device__ __forceinline__ void gload16(const void* g, void* l) {
  __builtin_amdgcn_global_load_lds(
      (const __attribute__((address_space(1))) unsigned int*)g,
      (__attribute__((address_space(3))) unsigned int*)l, 16, 0, 0);
}

// ---------------------------------------------------------------------------
// Direct fp32 conv (d3: Cout=3+tanh). Optional CL hi/lo output.
// ---------------------------------------------------------------------------
template <int K, int S, int DIL>
__global__ __launch_bounds__(256) void conv2d_k(
    const float* __restrict__ x, const float* __restrict__ w,
    const float* __restrict__ bias, float* y, u16* clh, u16* cll, int WpO,
    int PoffO, long o_fstride, int N, int Cin, int Hin, int Win, int Cout,
    int Hout, int Wout, int pad, int act) {
  constexpr int TW = 8;
  constexpr int XL = (TW - 1) * S + (K - 1) * DIL + 1;
  int wq = (Wout + TW - 1) / TW;
  long gid = (long)blockIdx.x * 256 + threadIdx.x;
  long total = (long)N * Cout * Hout * wq;
  if (gid >= total) return;
  int xg = (int)(gid % wq);
  long r = gid / wq;
  int yo = (int)(r % Hout);
  r /= Hout;
  int oc = (int)(r % Cout);
  int n = (int)(r / Cout);

  float bv = bias[oc];
  float acc[TW];
#pragma unroll
  for (int j = 0; j < TW; ++j) acc[j] = bv;

  int xo0 = xg * TW;
  int xi0 = xo0 * S - pad;
  const float* xn = x + (long)n * Cin * Hin * Win;
  const float* wb = w + (long)oc * Cin * K * K;

  for (int ic = 0; ic < Cin; ++ic) {
    const float* xc = xn + (long)ic * Hin * Win;
    const float* wc = wb + ic * (K * K);
#pragma unroll
    for (int ky = 0; ky < K; ++ky) {
      int yi = yo * S - pad + ky * DIL;
      if ((unsigned)yi < (unsigned)Hin) {
        const float* row = xc + (long)yi * Win;
        float xr[XL];
#pragma unroll
        for (int i2 = 0; i2 < XL; ++i2) {
          int xi = xi0 + i2;
          xr[i2] = ((unsigned)xi < (unsigned)Win) ? row[xi] : 0.f;
        }
#pragma unroll
        for (int kx = 0; kx < K; ++kx) {
          float wv = wc[ky * K + kx];
#pragma unroll
          for (int j = 0; j < TW; ++j)
            acc[j] = fmaf(wv, xr[j * S + kx * DIL], acc[j]);
        }
      }
    }
  }

#pragma unroll
  for (int j = 0; j < TW; ++j) {
    if (xo0 + j < Wout) {
      float v = acc[j];
      if (act == ACT_LEAKY)
        v = v >= 0.f ? v : 0.2f * v;
      else if (act == ACT_TANH)
        v = tanhf(v);
      if (y) y[(((long)n * Cout + oc) * Hout + yo) * Wout + xo0 + j] = v;
      if (clh) {
        long off = (long)n * o_fstride +
                   ((long)(yo + PoffO) * WpO + (xo0 + j + PoffO)) * Cout + oc;
        u16 h = f2bf(v);
        clh[off] = h;
        if (cll) cll[off] = f2bf(v - bf2f(h));
      }
    }
  }
}

// ---------------------------------------------------------------------------
// enc0 (3->64, stride2) with oc-innermost lanes -> coalesced CL writes.
// Writes HI only (lo stream of XCL2 is never read).
// ---------------------------------------------------------------------------
__global__ __launch_bounds__(256) void conv_enc0_cl(
    const float* __restrict__ x, const float* __restrict__ w,
    const float* __restrict__ bias, u16* __restrict__ clh) {
  __shared__ float ws[64][29];
  int t = threadIdx.x;
  for (int i = t; i < 64 * 27; i += 256) ws[i / 27][i % 27] = w[i];
  __syncthreads();
  int oc = t & 63;
  float bv = bias[oc];
  long s0 = (long)blockIdx.x * 32 + (t >> 6);
#pragma unroll
  for (int step = 0; step < 8; ++step) {
    long s = s0 + step * 4;
    int xo = (int)(s % 320);
    long r = s / 320;
    int yo = (int)(r % 60);
    int n = (int)(r / 60);
    float acc = bv;
    for (int ic = 0; ic < 3; ++ic) {
      const float* xp = x + ((long)n * 3 + ic) * 76800;
      const float* wp = ws[oc] + ic * 9;
#pragma unroll
      for (int ky = 0; ky < 3; ++ky) {
        int yi = yo * 2 - 1 + ky;
        if ((unsigned)yi < 120u) {
#pragma unroll
          for (int kx = 0; kx < 3; ++kx) {
            int xi = xo * 2 - 1 + kx;
            if ((unsigned)xi < 640u)
              acc = fmaf(wp[ky * 3 + kx], xp[yi * 640 + xi], acc);
          }
        }
      }
    }
    float v = acc >= 0.f ? acc : 0.2f * acc;
    long off = (long)n * 1327104 + ((long)(yo + 2) * 324 + (xo + 2)) * 64 + oc;
    clh[off] = f2bf(v);
  }
}

// ---------------------------------------------------------------------------
// LDS-staged MFMA implicit-GEMM conv, 2-term Ah*(Bh+Bl), 2-phase dbuf.
// Ol may be null -> hi-only output (lo dead for that buffer).
// ---------------------------------------------------------------------------
template <int WM, int WN>
__global__ __launch_bounds__(256) void conv_gemm_lds(
    const u16* __restrict__ Ah, const u16* __restrict__ Al,
    const u16* __restrict__ Bh, const u16* __restrict__ Bl,
    const float* __restrict__ bias, int Cin, int Cout, int Hout, int Wout,
    int Wp, int Poff, int S, int DIL, int pad, int taps, long a_fstride,
    int act, float* yout, long y_fstride, u16* Oh, u16* Ol, long o_fstride,
    int WpO, int PoffO, int useres) {
  constexpr int TM = WM * 64, TN = WN * 64;
  __shared__ u16 AsH[2 * TM * 32], BsH[2 * TN * 32], BsL[2 * TN * 32];
  int t = threadIdx.x;
  int lane = t & 63;
  int w = t >> 6;
  int wr = w / WN, wc = w % WN;
  int l15 = lane & 15, l16 = lane >> 4;
  int HW = Hout * Wout;
  int row0 = blockIdx.x * TM;
  int col0 = blockIdx.y * TN;
  const u16* Afh = Ah + (long)blockIdx.z * a_fstride;

  int rs = t >> 2;
  int cs = (t & 3) * 8;
  long abase[WM];
#pragma unroll
  for (int c = 0; c < WM; ++c) {
    int s = row0 + rs + 64 * c;
    if (s >= HW) s = HW - 1;
    int yo = s / Wout, xo = s - yo * Wout;
    int yb = yo * S - pad + Poff, xb = xo * S - pad + Poff;
    abase[c] = ((long)yb * Wp + xb) * Cin + cs;
  }
  long bbase[WN];
#pragma unroll
  for (int c = 0; c < WN; ++c)
    bbase[c] = (long)(col0 + rs + 64 * c) * Cin + cs;
  int ldst = w * 512;

  int nic = Cin >> 5;
  int NK = taps * nic;
  auto STAGE = [&](int kk, int buf) {
    int tap = kk / nic;
    int ic0 = (kk - tap * nic) << 5;
    int ky = tap / 3, kx = tap - ky * 3;
    long aoff = ((long)ky * DIL * Wp + kx * DIL) * Cin + ic0;
    long boff = (long)tap * Cout * Cin + ic0;
    u16* aB = AsH + buf * (TM * 32);
    u16* bhB = BsH + buf * (TN * 32);
    u16* blB = BsL + buf * (TN * 32);
#pragma unroll
    for (int c = 0; c < WM; ++c)
      gload16(Afh + abase[c] + aoff, aB + c * 2048 + ldst);
#pragma unroll
    for (int c = 0; c < WN; ++c) {
      gload16(Bh + bbase[c] + boff, bhB + c * 2048 + ldst);
      gload16(Bl + bbase[c] + boff, blB + c * 2048 + ldst);
    }
  };

  f32x4 acc[4][4];
#pragma unroll
  for (int m = 0; m < 4; ++m)
#pragma unroll
    for (int n = 0; n < 4; ++n) acc[m][n] = (f32x4){0.f, 0.f, 0.f, 0.f};

  STAGE(0, 0);
  __syncthreads();
  int cur = 0;
  for (int kk = 0; kk < NK; ++kk) {
    if (kk + 1 < NK) STAGE(kk + 1, cur ^ 1);
    const u16* aB = AsH + cur * (TM * 32);
    const u16* bhB = BsH + cur * (TN * 32);
    const u16* blB = BsL + cur * (TN * 32);
    bf16x8 ah[4];
#pragma unroll
    for (int m = 0; m < 4; ++m) {
      int rrow = wr * 64 + m * 16 + l15;
      ah[m] = *(const bf16x8*)(aB + rrow * 32 + l16 * 8);
    }
#pragma unroll
    for (int n = 0; n < 4; ++n) {
      int rcol = wc * 64 + n * 16 + l15;
      bf16x8 bh = *(const bf16x8*)(bhB + rcol * 32 + l16 * 8);
      bf16x8 bl = *(const bf16x8*)(blB + rcol * 32 + l16 * 8);
#pragma unroll
      for (int m = 0; m < 4; ++m) {
        acc[m][n] = MFMA(ah[m], bh, acc[m][n]);
        acc[m][n] = MFMA(ah[m], bl, acc[m][n]);
      }
    }
    __syncthreads();
    cur ^= 1;
  }

  float* yf = yout ? yout + (long)blockIdx.z * y_fstride : nullptr;
  u16* Ofh = Oh ? Oh + (long)blockIdx.z * o_fstride : nullptr;
  u16* Ofl = Ol ? Ol + (long)blockIdx.z * o_fstride : nullptr;
#pragma unroll
  for (int m = 0; m < 4; ++m) {
#pragma unroll
    for (int r = 0; r < 4; ++r) {
      int s = row0 + wr * 64 + m * 16 + l16 * 4 + r;
      if (s >= HW) continue;
      int yo = s / Wout, xo = s - yo * Wout;
      long clbase = 0;
      if (Ofh) clbase = ((long)(yo + PoffO) * WpO + (xo + PoffO)) * Cout;
#pragma unroll
      for (int n = 0; n < 4; ++n) {
        int oc = col0 + wc * 64 + n * 16 + l15;
        float v = acc[m][n][r] + bias[oc];
        if (act == ACT_LEAKY) v = v >= 0.f ? v : 0.2f * v;
        if (Ofh) {
          long off = clbase + oc;
          if (useres) v += bf2f(Ofh[off]) + bf2f(Ofl[off]);
          u16 h = f2bf(v);
          Ofh[off] = h;
          if (Ofl) Ofl[off] = f2bf(v - bf2f(h));
        }
        if (yf) yf[((long)oc * Hout + yo) * Wout + xo] = v;
      }
    }
  }
}

// ---------------------------------------------------------------------------
// Fused QKV 1x1 GEMM, 2-term, 2-phase dbuf. Tile 256x64, 4 waves.
// Token layout d = dm*64 + c. Q stores HI only.
// ---------------------------------------------------------------------------
__global__ __launch_bounds__(256) void qkv3_gemm_lds(
    const u16* __restrict__ Ah, const u16* __restrict__ Al, long a_fstride,
    int Wp, int Poff, const u16* __restrict__ qwh, const u16* __restrict__ qwl,
    const u16* __restrict__ kwh, const u16* __restrict__ kwl,
    const u16* __restrict__ vwh, const u16* __restrict__ vwl,
    const float* __restrict__ qbias, const float* __restrict__ kbias,
    const float* __restrict__ vbias, const int* __restrict__ nmap,
    const int* __restrict__ dmap, int ohow, int Dd, int pp, int NtokPad,
    float scale, u16* __restrict__ tqh, u16* __restrict__ tql,
    u16* __restrict__ tkh, u16* __restrict__ tkl, u16* __restrict__ tvh,
    u16* __restrict__ tvl) {
  __shared__ u16 AsH[2 * 256 * 32], BsH[2 * 64 * 32], BsL[2 * 64 * 32];
  int t = threadIdx.x;
  int lane = t & 63;
  int w = t >> 6;
  int l15 = lane & 15, l16 = lane >> 4;
  int row0 = blockIdx.x * 256;
  int frame = blockIdx.z;
  const u16* Afh = Ah + (long)frame * a_fstride;

  int rs = t >> 2;
  int cs = (t & 3) * 8;
  long abase[4];
#pragma unroll
  for (int c = 0; c < 4; ++c) {
    int s = row0 + rs + 64 * c;
    if (s >= 4800) s = 4799;
    int yo = s / 160, xo = s - yo * 160;
    abase[c] = ((long)(yo + Poff) * Wp + (xo + Poff)) * 256 + cs;
  }
  long bbase = (long)rs * 256 + cs;
  int ldst = w * 512;

  for (int mat = 0; mat < 3; ++mat) {
    const u16* Bh = mat == 0 ? qwh : mat == 1 ? kwh : vwh;
    const u16* Bl = mat == 0 ? qwl : mat == 1 ? kwl : vwl;
    const float* bias = mat == 0 ? qbias : mat == 1 ? kbias : vbias;
    u16* tH = mat == 0 ? tqh : mat == 1 ? tkh : tvh;
    u16* tL = mat == 0 ? tql : mat == 1 ? tkl : tvl;

    auto STAGE = [&](int kk, int buf) {
      int ic0 = kk << 5;
      u16* aB = AsH + buf * (256 * 32);
      u16* bhB = BsH + buf * (64 * 32);
      u16* blB = BsL + buf * (64 * 32);
#pragma unroll
      for (int c = 0; c < 4; ++c)
        gload16(Afh + abase[c] + ic0, aB + c * 2048 + ldst);
      gload16(Bh + bbase + ic0, bhB + ldst);
      gload16(Bl + bbase + ic0, blB + ldst);
    };

    f32x4 acc[4][4];
#pragma unroll
    for (int m = 0; m < 4; ++m)
#pragma unroll
      for (int n = 0; n < 4; ++n) acc[m][n] = (f32x4){0.f, 0.f, 0.f, 0.f};

    STAGE(0, 0);
    __syncthreads();
    int cur = 0;
    for (int kk = 0; kk < 8; ++kk) {
      if (kk + 1 < 8) STAGE(kk + 1, cur ^ 1);
      const u16* aB = AsH + cur * (256 * 32);
      const u16* bhB = BsH + cur * (64 * 32);
      const u16* blB = BsL + cur * (64 * 32);
      bf16x8 ah[4];
#pragma unroll
      for (int m = 0; m < 4; ++m) {
        int rrow = w * 64 + m * 16 + l15;
        ah[m] = *(const bf16x8*)(aB + rrow * 32 + l16 * 8);
      }
#pragma unroll
      for (int n = 0; n < 4; ++n) {
        int rcol = n * 16 + l15;
        bf16x8 bh = *(const bf16x8*)(bhB + rcol * 32 + l16 * 8);
        bf16x8 bl = *(const bf16x8*)(blB + rcol * 32 + l16 * 8);
#pragma unroll
        for (int m = 0; m < 4; ++m) {
          acc[m][n] = MFMA(ah[m], bh, acc[m][n]);
          acc[m][n] = MFMA(ah[m], bl, acc[m][n]);
        }
      }
      __syncthreads();
      cur ^= 1;
    }

#pragma unroll
    for (int m = 0; m < 4; ++m) {
#pragma unroll
      for (int r = 0; r < 4; ++r) {
        int s = row0 + w * 64 + m * 16 + l16 * 4 + r;
        if (s >= 4800) continue;
        int nm = nmap[s], dm = dmap[s];
        int ntok = frame * ohow + nm;
#pragma unroll
        for (int n = 0; n < 4; ++n) {
          int c = n * 16 + l15;
          float v = acc[m][n][r] + bias[c];
          if (mat == 0) v *= scale;
          int d = dm * 64 + c;
          long off = (mat == 2) ? ((long)d * NtokPad + ntok)
                                : ((long)ntok * Dd + d);
          u16 h = f2bf(v);
          tH[off] = h;
          if (mat != 0) tL[off] = f2bf(v - bf2f(h));
        }
      }
    }
  }
}

// ---------------------------------------------------------------------------
// QK GEMM, 2-term Qh*(Kh+Kl), 2-phase dbuf. Tile 128x128.
// ---------------------------------------------------------------------------
__global__ __launch_bounds__(256) void attn_gemm_lds(
    const u16* __restrict__ Ah, const u16* __restrict__ Al, int lda, int Mrows,
    const u16* __restrict__ Bh, const u16* __restrict__ Bl, int ldb,
    int Nclamp, int Kpart, int Nvalid, int mode, float* outf, int ldo,
    long partstride, u16* __restrict__ Oh, u16* __restrict__ Ol,
    const int* __restrict__ rowbase, const int* __restrict__ doff) {
  __shared__ u16 AsH[2 * 128 * 32], BsH[2 * 128 * 32], BsL[2 * 128 * 32];
  int t = threadIdx.x;
  int lane = t & 63;
  int w = t >> 6;
  int wc = w & 1, wr = w >> 1;
  int l15 = lane & 15, l16 = lane >> 4;
  int row0 = blockIdx.x * 128;
  int col0 = blockIdx.y * 128;
  int kbase = blockIdx.z * Kpart;
  if (outf) outf += (long)blockIdx.z * partstride;

  int rs = t >> 2;
  int cs = (t & 3) * 8;
  long abase[2], bbase[2];
#pragma unroll
  for (int c = 0; c < 2; ++c) {
    int sr = row0 + rs + 64 * c;
    if (sr >= Mrows) sr = Mrows - 1;
    abase[c] = (long)sr * lda + cs;
    int cc = col0 + rs + 64 * c;
    if (cc >= Nclamp) cc = Nclamp - 1;
    bbase[c] = (long)cc * ldb + cs;
  }
  int ldst = w * 512;

  int NK = Kpart >> 5;
  auto STAGE = [&](int kk, int buf) {
    long k = kbase + ((long)kk << 5);
    u16* aB = AsH + buf * (128 * 32);
    u16* bhB = BsH + buf * (128 * 32);
    u16* blB = BsL + buf * (128 * 32);
#pragma unroll
    for (int c = 0; c < 2; ++c) {
      gload16(Ah + abase[c] + k, aB + c * 2048 + ldst);
      gload16(Bh + bbase[c] + k, bhB + c * 2048 + ldst);
      gload16(Bl + bbase[c] + k, blB + c * 2048 + ldst);
    }
  };

  f32x4 acc[4][4];
#pragma unroll
  for (int m = 0; m < 4; ++m)
#pragma unroll
    for (int n = 0; n < 4; ++n) acc[m][n] = (f32x4){0.f, 0.f, 0.f, 0.f};

  STAGE(0, 0);
  __syncthreads();
  int cur = 0;
  for (int kk = 0; kk < NK; ++kk) {
    if (kk + 1 < NK) STAGE(kk + 1, cur ^ 1);
    const u16* aB = AsH + cur * (128 * 32);
    const u16* bhB = BsH + cur * (128 * 32);
    const u16* blB = BsL + cur * (128 * 32);
    bf16x8 ah[4];
#pragma unroll
    for (int m = 0; m < 4; ++m) {
      int rrow = wr * 64 + m * 16 + l15;
      ah[m] = *(const bf16x8*)(aB + rrow * 32 + l16 * 8);
    }
#pragma unroll
    for (int n = 0; n < 4; ++n) {
      int rcol = wc * 64 + n * 16 + l15;
      bf16x8 bh = *(const bf16x8*)(bhB + rcol * 32 + l16 * 8);
      bf16x8 bl = *(const bf16x8*)(blB + rcol * 32 + l16 * 8);
#pragma unroll
      for (int m = 0; m < 4; ++m) {
        acc[m][n] = MFMA(ah[m], bh, acc[m][n]);
        acc[m][n] = MFMA(ah[m], bl, acc[m][n]);
      }
    }
    __syncthreads();
    cur ^= 1;
  }

#pragma unroll
  for (int m = 0; m < 4; ++m) {
#pragma unroll
    for (int r = 0; r < 4; ++r) {
      int sr = row0 + wr * 64 + m * 16 + l16 * 4 + r;
      if (sr >= Mrows) continue;
#pragma unroll
      for (int n = 0; n < 4; ++n) {
        int c = col0 + wc * 64 + n * 16 + l15;
        if (c >= Nvalid) continue;
        float v = acc[m][n][r];
        if (mode == 0) {
          outf[(long)sr * ldo + c] = v;
        } else {
          long off = (long)rowbase[sr] + doff[c];
          u16 h = f2bf(v);
          Oh[off] = h;
          if (Ol) Ol[off] = f2bf(v - bf2f(h));
        }
      }
    }
  }
}

// ---------------------------------------------------------------------------
// PV GEMM, 2-term Ph*(Vh+Vl), 2-phase dbuf. A = fp32 P rows (hi on the fly).
// Ol may be null (hi-only scatter).
// ---------------------------------------------------------------------------
__global__ __launch_bounds__(256) void attn_pv_lds(
    const float* __restrict__ P, int lda, int Mrows,
    const u16* __restrict__ Bh, const u16* __restrict__ Bl, int ldb,
    int Nclamp, int Kpart, int Nvalid, int mode, float* outf, int ldo,
    long partstride, u16* __restrict__ Oh, u16* __restrict__ Ol,
    const int* __restrict__ rowbase, const int* __restrict__ doff) {
  __shared__ float Asf[2 * 128 * 32];
  __shared__ u16 BsH[2 * 128 * 32], BsL[2 * 128 * 32];
  int t = threadIdx.x;
  int lane = t & 63;
  int w = t >> 6;
  int wc = w & 1, wr = w >> 1;
  int l15 = lane & 15, l16 = lane >> 4;
  int row0 = blockIdx.x * 128;
  int col0 = blockIdx.y * 128;
  int kbase = blockIdx.z * Kpart;
  if (outf) outf += (long)blockIdx.z * partstride;

  int arow = t >> 3;
  int acol = (t & 7) * 4;
  long abase[4];
#pragma unroll
  for (int j = 0; j < 4; ++j) {
    int r = row0 + arow + 32 * j;
    if (r >= Mrows) r = Mrows - 1;
    abase[j] = (long)r * lda + acol;
  }
  int rs = t >> 2;
  int cs = (t & 3) * 8;
  long bbase[2];
#pragma unroll
  for (int c = 0; c < 2; ++c) {
    int cc = col0 + rs + 64 * c;
    if (cc >= Nclamp) cc = Nclamp - 1;
    bbase[c] = (long)cc * ldb + cs;
  }
  int ldst = w * 512;

  int NK = Kpart >> 5;
  auto STAGE = [&](int kk, int buf) {
    long k = kbase + ((long)kk << 5);
    float* aB = Asf + buf * (128 * 32);
    u16* bhB = BsH + buf * (128 * 32);
    u16* blB = BsL + buf * (128 * 32);
#pragma unroll
    for (int j = 0; j < 4; ++j)
      gload16(P + abase[j] + k, aB + (w * 64 + 256 * j) * 4);
#pragma unroll
    for (int c = 0; c < 2; ++c) {
      gload16(Bh + bbase[c] + k, bhB + c * 2048 + ldst);
      gload16(Bl + bbase[c] + k, blB + c * 2048 + ldst);
    }
  };

  f32x4 acc[4][4];
#pragma unroll
  for (int m = 0; m < 4; ++m)
#pragma unroll
    for (int n = 0; n < 4; ++n) acc[m][n] = (f32x4){0.f, 0.f, 0.f, 0.f};

  STAGE(0, 0);
  __syncthreads();
  int cur = 0;
  for (int kk = 0; kk < NK; ++kk) {
    if (kk + 1 < NK) STAGE(kk + 1, cur ^ 1);
    const float* aB = Asf + cur * (128 * 32);
    const u16* bhB = BsH + cur * (128 * 32);
    const u16* blB = BsL + cur * (128 * 32);
    bf16x8 ah[4];
#pragma unroll
    for (int m = 0; m < 4; ++m) {
      int rrow = wr * 64 + m * 16 + l15;
      const float* ap = aB + rrow * 32 + l16 * 8;
      f32x4 p0 = *(const f32x4*)(ap);
      f32x4 p1 = *(const f32x4*)(ap + 4);
#pragma unroll
      for (int e = 0; e < 4; ++e) {
        ah[m][e] = (short)f2bf(p0[e]);
        ah[m][4 + e] = (short)f2bf(p1[e]);
      }
    }
#pragma unroll
    for (int n = 0; n < 4; ++n) {
      int rcol = wc * 64 + n * 16 + l15;
      bf16x8 bh = *(const bf16x8*)(bhB + rcol * 32 + l16 * 8);
      bf16x8 bl = *(const bf16x8*)(blB + rcol * 32 + l16 * 8);
#pragma unroll
      for (int m = 0; m < 4; ++m) {
        acc[m][n] = MFMA(ah[m], bh, acc[m][n]);
        acc[m][n] = MFMA(ah[m], bl, acc[m][n]);
      }
    }
    __syncthreads();
    cur ^= 1;
  }

#pragma unroll
  for (int m = 0; m < 4; ++m) {
#pragma unroll
    for (int r = 0; r < 4; ++r) {
      int sr = row0 + wr * 64 + m * 16 + l16 * 4 + r;
      if (sr >= Mrows) continue;
#pragma unroll
      for (int n = 0; n < 4; ++n) {
        int c = col0 + wc * 64 + n * 16 + l15;
        if (c >= Nvalid) continue;
        float v = acc[m][n][r];
        if (mode == 0) {
          outf[(long)sr * ldo + c] = v;
        } else {
          long off = (long)rowbase[sr] + doff[c];
          u16 h = f2bf(v);
          Oh[off] = h;
          if (Ol) Ol[off] = f2bf(v - bf2f(h));
        }
      }
    }
  }
}

// ---------------------------------------------------------------------------
__global__ __launch_bounds__(256) void reduce_scatter(
    const float* __restrict__ parts, int nparts, long pstride, int rows, int N,
    int mode, float* outf, u16* __restrict__ Oh, u16* __restrict__ Ol,
    const int* __restrict__ rowbase, const int* __restrict__ doff) {
  long gid = (long)blockIdx.x * 256 + threadIdx.x;
  long tot = (long)rows * N;
  if (gid >= tot) return;
  float s = 0.f;
  for (int p = 0; p < nparts; ++p) s += parts[p * pstride + gid];
  if (mode == 0) {
    outf[gid] = s;
  } else {
    int r = (int)(gid / N), c = (int)(gid % N);
    long off = (long)rowbase[r] + doff[c];
    u16 h = f2bf(s);
    Oh[off] = h;
    if (Ol) Ol[off] = f2bf(s - bf2f(h));
  }
}

// ---------------------------------------------------------------------------
__global__ __launch_bounds__(256) void softmax_ip(float* __restrict__ S,
                                                  int Ntok, int NtokPad) {
  int row = blockIdx.x;
  float* p = S + (long)row * NtokPad;
  __shared__ float red[256];
  int t = threadIdx.x;
  float m = -1e30f;
  for (int i = t; i < Ntok; i += 256) m = fmaxf(m, p[i]);
  red[t] = m;
  __syncthreads();
  for (int s = 128; s > 0; s >>= 1) {
    if (t < s) red[t] = fmaxf(red[t], red[t + s]);
    __syncthreads();
  }
  m = red[0];
  __syncthreads();
  float sum = 0.f;
  for (int i = t; i < Ntok; i += 256) sum += __expf(p[i] - m);
  red[t] = sum;
  __syncthreads();
  for (int s = 128; s > 0; s >>= 1) {
    if (t < s) red[t] += red[t + s];
    __syncthreads();
  }
  float inv = 1.f / red[0];
  __syncthreads();
  for (int i = t; i < Ntok; i += 256) p[i] = __expf(p[i] - m) * inv;
  for (int i = Ntok + t; i < NtokPad; i += 256) p[i] = 0.f;
}

// ---------------------------------------------------------------------------
__global__ __launch_bounds__(256) void wt_build(const float* __restrict__ w,
                                                int Cout, int Cin, int taps,
                                                u16* __restrict__ Wh,
                                                u16* __restrict__ Wl) {
  long gid = (long)blockIdx.x * 256 + threadIdx.x;
  long tot = (long)taps * Cout * Cin;
  if (gid >= tot) return;
  int ic = (int)(gid % Cin);
  long r = gid / Cin;
  int oc = (int)(r % Cout);
  int tap = (int)(r / Cout);
  float v = w[((long)oc * Cin + ic) * taps + tap];
  splitw(v, &Wh[gid], &Wl[gid]);
}

// build to/ff1/ff2 weight splits (256x256x9 each) in one dispatch
__global__ __launch_bounds__(256) void wt3_build(const float* __restrict__ w0,
                                                 const float* __restrict__ w1,
                                                 const float* __restrict__ w2,
                                                 u16* __restrict__ base) {
  long gid = (long)blockIdx.x * 256 + threadIdx.x;
  if (gid >= 3L * 589824) return;
  int mat = (int)(gid / 589824);
  int idx = (int)(gid - (long)mat * 589824);
  const float* w = mat == 0 ? w0 : mat == 1 ? w1 : w2;
  int ic = idx & 255;
  int r = idx >> 8;
  int oc = r & 255;
  int tap = r >> 8;
  float v = w[((long)oc * 256 + ic) * 9 + tap];
  u16* dst = base + (long)mat * 1179648;
  splitw(v, &dst[idx], &dst[589824 + idx]);
}

// fused q/k/v 1x1 weight split build, ALL 4 groups in one dispatch.
__global__ __launch_bounds__(256) void wtqkv_build_all(
    const float* __restrict__ wq, const float* __restrict__ wk,
    const float* __restrict__ wv, u16* __restrict__ qh, u16* __restrict__ ql,
    u16* __restrict__ kh, u16* __restrict__ kl, u16* __restrict__ vh,
    u16* __restrict__ vl) {
  int gid = blockIdx.x * 256 + threadIdx.x;
  if (gid >= 4 * 64 * 256) return;
  int ic = gid & 255;
  int c = (gid >> 8) & 63;
  int g = gid >> 14;
  long src = (long)(g * 64 + c) * 256 + ic;
  splitw(wq[src], &qh[gid], &ql[gid]);
  splitw(wk[src], &kh[gid], &kl[gid]);
  splitw(wv[src], &vh[gid], &vl[gid]);
}

// ---------------------------------------------------------------------------
__global__ __launch_bounds__(256) void maps_build(int ph, int pw, int ow,
                                                  int* __restrict__ nmap,
                                                  int* __restrict__ dmap) {
  int s = blockIdx.x * 256 + threadIdx.x;
  if (s >= 4800) return;
  int y = s / 160, x = s - y * 160;
  int i = y / ph, yy = y - i * ph;
  int j = x / pw, xx = x - j * pw;
  nmap[s] = i * ow + j;
  dmap[s] = yy * pw + xx;
}

// d = dm*64 + ch (channels innermost). doff[d] contiguous in ch.
__global__ __launch_bounds__(256) void luts_build(int ph, int pw, int ohow,
                                                  int ow, int pp, int Ntok,
                                                  int Dd, int gbase,
                                                  int* __restrict__ rowbase,
                                                  int* __restrict__ doff) {
  int gid = blockIdx.x * 256 + threadIdx.x;
  if (gid < Ntok) {
    int tt = gid / ohow, rem = gid - tt * ohow;
    int i = rem / ow, j = rem - i * ow;
    rowbase[gid] =
        tt * (32 * 162 * 256) + ((i * ph + 1) * 162 + (j * pw + 1)) * 256;
  }
  if (gid < Dd) {
    int ch = gid & 63;
    int dm = gid >> 6;
    int yy = dm / pw, xx = dm - yy * pw;
    doff[gid] = (yy * 162 + xx) * 256 + gbase + ch;
  }
}

// ---------------------------------------------------------------------------
// Bilinear x2 upsample (align_corners) CL hi/lo -> CL, full padded write.
// ol may be null (hi-only destination). blockIdx.z = frame.
// ---------------------------------------------------------------------------
__global__ __launch_bounds__(256) void up_cl2cl_pad(
    const u16* __restrict__ sh, const u16* __restrict__ sl,
    u16* __restrict__ oh, u16* __restrict__ ol, long s_fs, long o_fs, int C,
    int H, int W, int Wps, int Poffs, int Hp, int Wpo, int Poffo) {
  sh += (long)blockIdx.z * s_fs;
  sl += (long)blockIdx.z * s_fs;
  oh += (long)blockIdx.z * o_fs;
  if (ol) ol += (long)blockIdx.z * o_fs;
  int Ho = 2 * H, Wo = 2 * W;
  long tot = (long)Hp * Wpo * C;
  long gid = (long)blockIdx.x * 256 + threadIdx.x;
  if (gid >= tot) return;
  int c = (int)(gid % C);
  long r = gid / C;
  int xp = (int)(r % Wpo);
  int yp = (int)(r / Wpo);
  int x = xp - Poffo, y = yp - Poffo;
  float v = 0.f;
  if ((unsigned)x < (unsigned)Wo && (unsigned)y < (unsigned)Ho) {
    float fy = (float)(y * (H - 1)) / (float)(Ho - 1);
    float fx = (float)(x * (W - 1)) / (float)(Wo - 1);
    int y0 = (int)fy, x0 = (int)fx;
    int y1 = min(y0 + 1, H - 1), x1 = min(x0 + 1, W - 1);
    float wy = fy - y0, wx = fx - x0;
    auto rd = [&](int cy, int cx) {
      long o = ((long)(cy + Poffs) * Wps + (cx + Poffs)) * C + c;
      return bf2f(sh[o]) + bf2f(sl[o]);
    };
    float r0 = rd(y0, x0) * (1.f - wx) + rd(y0, x1) * wx;
    float r1 = rd(y1, x0) * (1.f - wx) + rd(y1, x1) * wx;
    v = r0 * (1.f - wy) + r1 * wy;
  }
  u16 h = f2bf(v);
  oh[gid] = h;
  if (ol) ol[gid] = f2bf(v - bf2f(h));
}

// ---------------------------------------------------------------------------
extern "C" void kernel_launch(void* const* d_in, const int* in_sizes, int n_in,
                              void* d_out, int out_size, void* d_ws,
                              size_t ws_size, hipStream_t stream) {
  const float* input = (const float*)d_in[0];
  const float* enc_w0 = (const float*)d_in[1];
  const float* enc_b0 = (const float*)d_in[2];
  const float* enc_w1 = (const float*)d_in[3];
  const float* enc_b1 = (const float*)d_in[4];
  const float* enc_w2 = (const float*)d_in[5];
  const float* enc_b2 = (const float*)d_in[6];
  const float* enc_w3 = (const float*)d_in[7];
  const float* enc_b3 = (const float*)d_in[8];
  const float* tq_w = (const float*)d_in[9];
  const float* tq_b = (const float*)d_in[10];
  const float* tk_w = (const float*)d_in[11];
  const float* tk_b = (const float*)d_in[12];
  const float* tv_w = (const float*)d_in[13];
  const float* tv_b = (const float*)d_in[14];
  const float* to_w = (const float*)d_in[15];
  const float* to_b = (const float*)d_in[16];
  const float* tf1_w = (const float*)d_in[17];
  const float* tf1_b = (const float*)d_in[18];
  const float* tf2_w = (const float*)d_in[19];
  const float* tf2_b = (const float*)d_in[20];
  const float* d0_w = (const float*)d_in[21];
  const float* d0_b = (const float*)d_in[22];
  const float* d1_w = (const float*)d_in[23];
  const float* d1_b = (const float*)d_in[24];
  const float* d2_w = (const float*)d_in[25];
  const float* d2_b = (const float*)d_in[26];
  const float* d3_w = (const float*)d_in[27];
  const float* d3_b = (const float*)d_in[28];
  float* out = (float*)d_out;

  // -------- workspace layout --------
  unsigned char* wsb = (unsigned char*)d_ws;
  size_t off = 0;
  auto alloc = [&](size_t bytes) {
    void* p = wsb + off;
    off = (off + bytes + 255) & ~(size_t)255;
    return p;
  };
  const long XCL_E = 22839296L;   // 16*34*164*256
  const long XCL2_E = 21233664L;  // 16*32*162*256
  const long QT_E = 4915200L;
  const long VT_E = 5111808L;
  u16* XCLh = (u16*)alloc(XCL_E * 2);
  u16* XCLl = (u16*)alloc(XCL_E * 2);
  u16* XCL2h = (u16*)alloc(XCL2_E * 2);
  u16* XCL2l = (u16*)alloc(XCL2_E * 2);
  u16* qth = (u16*)alloc(QT_E * 2);
  u16* qtl = (u16*)alloc(QT_E * 2);
  u16* kth = (u16*)alloc(QT_E * 2);
  u16* ktl = (u16*)alloc(QT_E * 2);
  u16* vth = (u16*)alloc(VT_E * 2);
  u16* vtl = (u16*)alloc(VT_E * 2);
  int* nmapA = (int*)alloc(4 * 4800 * 4);
  int* dmapA = (int*)alloc(4 * 4800 * 4);
  int* rowbaseA = (int*)alloc(7120 * 4);
  int* doffA = (int*)alloc(93248 * 4);
  u16* qwh = (u16*)alloc(65536 * 2);
  u16* qwl = (u16*)alloc(65536 * 2);
  u16* kwh = (u16*)alloc(65536 * 2);
  u16* kwl = (u16*)alloc(65536 * 2);
  u16* vwh = (u16*)alloc(65536 * 2);
  u16* vwl = (u16*)alloc(65536 * 2);
  size_t fixed_end = off;
  size_t avail = ws_size > fixed_end ? ws_size - fixed_end : 0;
  size_t SCB = avail > 4096 ? avail - 4096 : 0;
  if (SCB > 104857600UL) SCB = 104857600UL;
  float* scores = (float*)alloc(SCB);
  size_t need = off;
  if (ws_size < need) return;  // fail loud, not crash
  long SCAPf = (long)(SCB / 4);
  if (SCAPf < 1800000) return;

  // encoder weight splits + trunk wt3 region overlay the scores region
  u16* Wth = (u16*)scores;
  u16* Wtl = Wth + 589824;
  u16* W3 = (u16*)scores;

  // ---- decoder buffers: overlay XCL2+token+scores region ----
  unsigned char* decbase = (unsigned char*)XCL2h;
  u16* dec0inH = (u16*)(decbase + 0);
  u16* dec0inL = (u16*)(decbase + 40886272);   // unused (lo dead)
  u16* dec0outH = (u16*)(decbase + 81772544);
  u16* dec0outL = (u16*)(decbase + 102215680); // unused (lo dead)
  u16* dec1outH = (u16*)(decbase + 122658816);
  u16* dec1outL = (u16*)(decbase + 132880384); // KEPT (up2 reads lo)
  u16* dec2inH = (u16*)(decbase + 0);
  u16* dec2inL = (u16*)(decbase + 20050944);   // unused (lo dead)
  float* dec2out = (float*)(decbase + 40101888);
  u16* Wd0h = (u16*)(decbase + 143101952);
  u16* Wd0l = Wd0h + 294912;
  u16* W1h = Wd0l + 294912;
  u16* W1l = W1h + 73728;
  u16* W2h = W1l + 73728;
  u16* W2l = W2h + 36864;
  const long D0IN_FS = 5110784, D0OUT_FS = 2555392, D1OUT_FS = 1277696;
  const long D2IN_FS = 5012736, D2OUT_FS = 4915200;

  const long FS_TR = 1427456;  // 34*164*256
  const long FS_T2 = 1327104;  // 32*162*256 == 64*324*64
  const long FS_E2 = 713728;   // 34*164*128

  static const int PWa[4] = {80, 32, 10, 5};
  static const int PHa[4] = {15, 6, 5, 3};
  static const int rbOff[4] = {0, 64, 464, 2000};
  static const int doOff[4] = {0, 76800, 89088, 92288};

  // -------- encoder --------
  hipMemsetAsync(XCLh, 0, XCL_E * 2, stream);
  hipMemsetAsync(XCL2h, 0, XCL2_E * 2, stream);
  hipMemsetAsync(vth, 0, VT_E * 2, stream);
  hipMemsetAsync(vtl, 0, VT_E * 2, stream);
  conv_enc0_cl<<<9600, 256, 0, stream>>>(input, enc_w0, enc_b0, XCL2h);
  {  // enc1: out XCL hi-only (lo dead: consumed hi-only, overwritten by enc3)
    wt_build<<<cdivu(9L * 64 * 64, 256), 256, 0, stream>>>(enc_w1, 64, 64, 9,
                                                           Wth, Wtl);
    conv_gemm_lds<4, 1><<<dim3(75, 1, 16), 256, 0, stream>>>(
        XCL2h, nullptr, Wth, Wtl, enc_b1, 64, 64, 60, 320, 324, 2, 1, 1, 1, 9,
        FS_T2, ACT_LEAKY, nullptr, 0, XCLh, nullptr, FS_T2, 324, 2, 0);
  }
  hipMemsetAsync(XCL2h, 0, XCL2_E * 2, stream);
  {  // enc2: out XCL2 hi-only
    wt_build<<<cdivu(9L * 128 * 64, 256), 256, 0, stream>>>(enc_w2, 128, 64, 9,
                                                            Wth, Wtl);
    conv_gemm_lds<2, 2><<<dim3(38, 1, 16), 256, 0, stream>>>(
        XCLh, nullptr, Wth, Wtl, enc_b2, 64, 128, 30, 160, 324, 2, 2, 1, 1, 9,
        FS_T2, ACT_LEAKY, nullptr, 0, XCL2h, nullptr, FS_E2, 164, 2, 0);
  }
  hipMemsetAsync(XCLh, 0, XCL_E * 2, stream);
  hipMemsetAsync(XCLl, 0, XCL_E * 2, stream);
  {  // enc3: out trunk XCL hi+lo (residual master)
    wt_build<<<cdivu(9L * 256 * 128, 256), 256, 0, stream>>>(enc_w3, 256, 128,
                                                             9, Wth, Wtl);
    conv_gemm_lds<2, 2><<<dim3(38, 2, 16), 256, 0, stream>>>(
        XCL2h, nullptr, Wth, Wtl, enc_b3, 128, 256, 30, 160, 164, 2, 1, 1, 1,
        9, FS_E2, ACT_LEAKY, nullptr, 0, XCLh, XCLl, FS_TR, 164, 2, 0);
  }
  hipMemsetAsync(XCL2h, 0, XCL2_E * 2, stream);

  // -------- token maps / scatter LUTs --------
  for (int g = 0; g < 4; ++g) {
    int ph = PHa[g], pw = PWa[g];
    int ohh = 30 / ph, oww = 160 / pw;
    int Ntok = 16 * ohh * oww, Dd = 64 * ph * pw, pp = ph * pw;
    maps_build<<<19, 256, 0, stream>>>(ph, pw, oww, nmapA + g * 4800,
                                       dmapA + g * 4800);
    int mx = Ntok > Dd ? Ntok : Dd;
    luts_build<<<cdivu(mx, 256), 256, 0, stream>>>(
        ph, pw, ohh * oww, oww, pp, Ntok, Dd, g * 64, rowbaseA + rbOff[g],
        doffA + doOff[g]);
  }

  // -------- transformer stack --------
  for (int l = 0; l < 8; ++l) {
    wtqkv_build_all<<<256, 256, 0, stream>>>(
        tq_w + (long)l * 65536, tk_w + (long)l * 65536,
        tv_w + (long)l * 65536, qwh, qwl, kwh, kwl, vwh, vwl);

    for (int g = 0; g < 4; ++g) {
      int ph = PHa[g], pw = PWa[g];
      int ohh = 30 / ph, oww = 160 / pw;
      int ohow = ohh * oww;
      int Ntok = 16 * ohow, Dd = 64 * ph * pw, pp = ph * pw;
      int NtokPad = (Ntok + 31) & ~31;
      float scale = 1.0f / sqrtf((float)Dd);
      const int* nmap = nmapA + g * 4800;
      const int* dmap = dmapA + g * 4800;
      const int* rowbase = rowbaseA + rbOff[g];
      const int* doffp = doffA + doOff[g];

      qkv3_gemm_lds<<<dim3(19, 1, 16), 256, 0, stream>>>(
          XCLh, nullptr, FS_TR, 164, 2, qwh + g * 16384, qwl + g * 16384,
          kwh + g * 16384, kwl + g * 16384, vwh + g * 16384, vwl + g * 16384,
          tq_b + l * 256 + g * 64, tk_b + l * 256 + g * 64,
          tv_b + l * 256 + g * 64, nmap, dmap, ohow, Dd, pp, NtokPad, scale,
          qth, qtl, kth, ktl, vth, vtl);

      if (g == 0) {
        float* scoresR = scores + 131072;
        attn_gemm_lds<<<dim3(1, 1, 32), 256, 0, stream>>>(
            qth, qtl, Dd, 64, kth, ktl, Dd, 64, 2400, 64, 0, scores, 64, 4096,
            nullptr, nullptr, nullptr, nullptr);
        reduce_scatter<<<16, 256, 0, stream>>>(scores, 32, 4096, 64, 64, 0,
                                               scoresR, nullptr, nullptr,
                                               nullptr, nullptr);
        softmax_ip<<<64, 256, 0, stream>>>(scoresR, 64, 64);
        attn_pv_lds<<<dim3(1, 600, 1), 256, 0, stream>>>(
            scoresR, 64, 64, vth, vtl, 64, Dd, 64, Dd, 1, nullptr, 0, 0,
            XCL2h, nullptr, rowbase, doffp);
      } else {
        long denom = (long)NtokPad + (g == 3 ? 3840 : 0);
        long cap = (SCAPf / denom) & ~127L;
        int chunk = (int)(cap < 128 ? 128 : cap);
        if (chunk > Ntok) chunk = Ntok;
        float* partials = scores + (long)chunk * NtokPad;
        for (int r0 = 0; r0 < Ntok; r0 += chunk) {
          int rows = Ntok - r0 < chunk ? Ntok - r0 : chunk;
          attn_gemm_lds<<<dim3(cdivu(rows, 128), cdivu(Ntok, 128), 1), 256, 0,
                          stream>>>(qth + (long)r0 * Dd, qtl + (long)r0 * Dd,
                                    Dd, rows, kth, ktl, Dd, Ntok, Dd, Ntok, 0,
                                    scores, NtokPad, 0, nullptr, nullptr,
                                    nullptr, nullptr);
          softmax_ip<<<rows, 256, 0, stream>>>(scores, Ntok, NtokPad);
          if (g == 3) {
            attn_pv_lds<<<dim3(cdivu(rows, 128), 8, 4), 256, 0, stream>>>(
                scores, NtokPad, rows, vth, vtl, NtokPad, Dd, 1280, Dd, 0,
                partials, 960, (long)rows * 960, nullptr, nullptr, nullptr,
                nullptr);
            reduce_scatter<<<cdivu((long)rows * 960, 256), 256, 0, stream>>>(
                partials, 4, (long)rows * 960, rows, 960, 1, nullptr, XCL2h,
                nullptr, rowbase + r0, doffp);
          } else {
            attn_pv_lds<<<dim3(cdivu(rows, 128), Dd / 128, 1), 256, 0,
                          stream>>>(scores, NtokPad, rows, vth, vtl, NtokPad,
                                    Dd, NtokPad, Dd, 1, nullptr, 0, 0, XCL2h,
                                    nullptr, rowbase + r0, doffp);
          }
        }
      }
    }

    wt3_build<<<6912, 256, 0, stream>>>(to_w + (long)l * 589824,
                                        tf1_w + (long)l * 589824,
                                        tf2_w + (long)l * 589824, W3);
    // out-conv: reads XCL2 hi; writes XCL hi+lo with residual
    conv_gemm_lds<2, 2><<<dim3(38, 2, 16), 256, 0, stream>>>(
        XCL2h, nullptr, W3, W3 + 589824, to_b + l * 256, 256, 256, 30, 160,
        162, 1, 1, 1, 1, 9, FS_T2, ACT_LEAKY, nullptr, 0, XCLh, XCLl, FS_TR,
        164, 2, 1);
    // ff1: writes XCL2 hi-only
    conv_gemm_lds<2, 2><<<dim3(38, 2, 16), 256, 0, stream>>>(
        XCLh, nullptr, W3 + 1179648, W3 + 1769472, tf1_b + l * 256, 256, 256,
        30, 160, 164, 2, 1, 2, 2, 9, FS_TR, ACT_LEAKY, nullptr, 0, XCL2h,
        nullptr, FS_T2, 162, 1, 0);
    // ff2 + residual: writes XCL hi+lo
    conv_gemm_lds<2, 2><<<dim3(38, 2, 16), 256, 0, stream>>>(
        XCL2h, nullptr, W3 + 2359296, W3 + 2949120, tf2_b + l * 256, 256, 256,
        30, 160, 162, 1, 1, 1, 1, 9, FS_T2, ACT_LEAKY, nullptr, 0, XCLh, XCLl,
        FS_TR, 164, 2, 1);
  }

  // -------- decoder: 4-frame front half, 2-frame back half --------
  hipMemsetAsync(decbase, 0, 144723968, stream);
  wt_build<<<cdivu(9L * 128 * 256, 256), 256, 0, stream>>>(d0_w, 128, 256, 9,
                                                           Wd0h, Wd0l);
  wt_build<<<cdivu(9L * 64 * 128, 256), 256, 0, stream>>>(d1_w, 64, 128, 9,
                                                          W1h, W1l);
  wt_build<<<cdivu(9L * 64 * 64, 256), 256, 0, stream>>>(d2_w, 64, 64, 9, W2h,
                                                         W2l);
  for (int f = 0; f < 16; f += 4) {
    up_cl2cl_pad<<<dim3(cdivu(62L * 322 * 256, 256), 1, 4), 256, 0, stream>>>(
        XCLh + (long)f * FS_TR, XCLl + (long)f * FS_TR, dec0inH, nullptr,
        FS_TR, D0IN_FS, 256, 30, 160, 164, 2, 62, 322, 1);
    conv_gemm_lds<2, 2><<<dim3(150, 1, 4), 256, 0, stream>>>(
        dec0inH, nullptr, Wd0h, Wd0l, d0_b, 256, 128, 60, 320, 322, 1, 1, 1, 1,
        9, D0IN_FS, ACT_LEAKY, nullptr, 0, dec0outH, nullptr, D0OUT_FS, 322, 1,
        0);
    conv_gemm_lds<4, 1><<<dim3(75, 1, 4), 256, 0, stream>>>(
        dec0outH, nullptr, W1h, W1l, d1_b, 128, 64, 60, 320, 322, 1, 1, 1, 1,
        9, D0OUT_FS, ACT_LEAKY, nullptr, 0, dec1outH, dec1outL, D1OUT_FS, 322,
        1, 0);
    for (int ff = 0; ff < 4; ff += 2) {
      up_cl2cl_pad<<<dim3(cdivu(122L * 642 * 64, 256), 1, 2), 256, 0,
                     stream>>>(dec1outH + (long)ff * D1OUT_FS,
                               dec1outL + (long)ff * D1OUT_FS, dec2inH,
                               nullptr, D1OUT_FS, D2IN_FS, 64, 60, 320, 322, 1,
                               122, 642, 1);
      conv_gemm_lds<4, 1><<<dim3(300, 1, 2), 256, 0, stream>>>(
          dec2inH, nullptr, W2h, W2l, d2_b, 64, 64, 120, 640, 642, 1, 1, 1, 1,
          9, D2IN_FS, ACT_LEAKY, dec2out, D2OUT_FS, nullptr, nullptr, 0, 0, 0,
          0);
      long tot = 2L * 3 * 120 * 80;
      conv2d_k<3, 1, 1><<<cdivu(tot, 256), 256, 0, stream>>>(
          dec2out, d3_w, d3_b, out + (long)(f + ff) * 230400, nullptr, nullptr,
          0, 0, 0, 2, 64, 120, 640, 3, 120, 640, 1, ACT_TANH);
    }
  }
}

// Round 17
// 25339.679 us; speedup vs baseline: 40.4782x; 1.0393x over previous
//
#include <hip/hip_runtime.h>
#include <hip/hip_bf16.h>
#include <math.h>

#define ACT_NONE 0
#define ACT_LEAKY 1
#define ACT_TANH 2

typedef __attribute__((ext_vector_type(8))) short bf16x8;
typedef __attribute__((ext_vector_type(4))) float f32x4;
typedef unsigned short u16;

#define MFMA(a, b, c) __builtin_amdgcn_mfma_f32_16x16x32_bf16((bf16x8)(a), (bf16x8)(b), (c), 0, 0, 0)

static inline unsigned cdivu(long a, long b) { return (unsigned)((a + b - 1) / b); }

__device__ __forceinline__ u16 f2bf(float x) {
  union { __hip_bfloat16 h; u16 u; } cv;
  cv.h = __float2bfloat16(x);
  return cv.u;
}
__device__ __forceinline__ float bf2f(u16 b) {
  union { u16 u; __hip_bfloat16 h; } cv;
  cv.u = b;
  return __bfloat162float(cv.h);
}
__device__ __forceinline__ void splitw(float v, u16* ph, u16* pl) {
  u16 h = f2bf(v);
  *ph = h;
  *pl = f2bf(v - bf2f(h));
}
// async global->LDS, 16B per lane; dest must be wave-uniform base (+lane*16)
__device__ __forceinline__ void gload16(const void* g, void* l) {
  __builtin_amdgcn_global_load_lds(
      (const __attribute__((address_space(1))) unsigned int*)g,
      (__attribute__((address_space(3))) unsigned int*)l, 16, 0, 0);
}

// ---------------------------------------------------------------------------
// Direct fp32 conv (d3: Cout=3+tanh). Optional CL hi/lo output.
// ---------------------------------------------------------------------------
template <int K, int S, int DIL>
__global__ __launch_bounds__(256) void conv2d_k(
    const float* __restrict__ x, const float* __restrict__ w,
    const float* __restrict__ bias, float* y, u16* clh, u16* cll, int WpO,
    int PoffO, long o_fstride, int N, int Cin, int Hin, int Win, int Cout,
    int Hout, int Wout, int pad, int act) {
  constexpr int TW = 8;
  constexpr int XL = (TW - 1) * S + (K - 1) * DIL + 1;
  int wq = (Wout + TW - 1) / TW;
  long gid = (long)blockIdx.x * 256 + threadIdx.x;
  long total = (long)N * Cout * Hout * wq;
  if (gid >= total) return;
  int xg = (int)(gid % wq);
  long r = gid / wq;
  int yo = (int)(r % Hout);
  r /= Hout;
  int oc = (int)(r % Cout);
  int n = (int)(r / Cout);

  float bv = bias[oc];
  float acc[TW];
#pragma unroll
  for (int j = 0; j < TW; ++j) acc[j] = bv;

  int xo0 = xg * TW;
  int xi0 = xo0 * S - pad;
  const float* xn = x + (long)n * Cin * Hin * Win;
  const float* wb = w + (long)oc * Cin * K * K;

  for (int ic = 0; ic < Cin; ++ic) {
    const float* xc = xn + (long)ic * Hin * Win;
    const float* wc = wb + ic * (K * K);
#pragma unroll
    for (int ky = 0; ky < K; ++ky) {
      int yi = yo * S - pad + ky * DIL;
      if ((unsigned)yi < (unsigned)Hin) {
        const float* row = xc + (long)yi * Win;
        float xr[XL];
#pragma unroll
        for (int i2 = 0; i2 < XL; ++i2) {
          int xi = xi0 + i2;
          xr[i2] = ((unsigned)xi < (unsigned)Win) ? row[xi] : 0.f;
        }
#pragma unroll
        for (int kx = 0; kx < K; ++kx) {
          float wv = wc[ky * K + kx];
#pragma unroll
          for (int j = 0; j < TW; ++j)
            acc[j] = fmaf(wv, xr[j * S + kx * DIL], acc[j]);
        }
      }
    }
  }

#pragma unroll
  for (int j = 0; j < TW; ++j) {
    if (xo0 + j < Wout) {
      float v = acc[j];
      if (act == ACT_LEAKY)
        v = v >= 0.f ? v : 0.2f * v;
      else if (act == ACT_TANH)
        v = tanhf(v);
      if (y) y[(((long)n * Cout + oc) * Hout + yo) * Wout + xo0 + j] = v;
      if (clh) {
        long off = (long)n * o_fstride +
                   ((long)(yo + PoffO) * WpO + (xo0 + j + PoffO)) * Cout + oc;
        u16 h = f2bf(v);
        clh[off] = h;
        if (cll) cll[off] = f2bf(v - bf2f(h));
      }
    }
  }
}

// ---------------------------------------------------------------------------
// enc0 (3->64, stride2) with oc-innermost lanes -> coalesced CL writes.
// ---------------------------------------------------------------------------
__global__ __launch_bounds__(256) void conv_enc0_cl(
    const float* __restrict__ x, const float* __restrict__ w,
    const float* __restrict__ bias, u16* __restrict__ clh) {
  __shared__ float ws[64][29];
  int t = threadIdx.x;
  for (int i = t; i < 64 * 27; i += 256) ws[i / 27][i % 27] = w[i];
  __syncthreads();
  int oc = t & 63;
  float bv = bias[oc];
  long s0 = (long)blockIdx.x * 32 + (t >> 6);
#pragma unroll
  for (int step = 0; step < 8; ++step) {
    long s = s0 + step * 4;
    int xo = (int)(s % 320);
    long r = s / 320;
    int yo = (int)(r % 60);
    int n = (int)(r / 60);
    float acc = bv;
    for (int ic = 0; ic < 3; ++ic) {
      const float* xp = x + ((long)n * 3 + ic) * 76800;
      const float* wp = ws[oc] + ic * 9;
#pragma unroll
      for (int ky = 0; ky < 3; ++ky) {
        int yi = yo * 2 - 1 + ky;
        if ((unsigned)yi < 120u) {
#pragma unroll
          for (int kx = 0; kx < 3; ++kx) {
            int xi = xo * 2 - 1 + kx;
            if ((unsigned)xi < 640u)
              acc = fmaf(wp[ky * 3 + kx], xp[yi * 640 + xi], acc);
          }
        }
      }
    }
    float v = acc >= 0.f ? acc : 0.2f * acc;
    long off = (long)n * 1327104 + ((long)(yo + 2) * 324 + (xo + 2)) * 64 + oc;
    clh[off] = f2bf(v);
  }
}

// ---------------------------------------------------------------------------
// LDS-staged MFMA implicit-GEMM conv, 2-term Ah*(Bh+Bl), 2-phase dbuf.
// ---------------------------------------------------------------------------
template <int WM, int WN>
__global__ __launch_bounds__(256) void conv_gemm_lds(
    const u16* __restrict__ Ah, const u16* __restrict__ Al,
    const u16* __restrict__ Bh, const u16* __restrict__ Bl,
    const float* __restrict__ bias, int Cin, int Cout, int Hout, int Wout,
    int Wp, int Poff, int S, int DIL, int pad, int taps, long a_fstride,
    int act, float* yout, long y_fstride, u16* Oh, u16* Ol, long o_fstride,
    int WpO, int PoffO, int useres) {
  constexpr int TM = WM * 64, TN = WN * 64;
  __shared__ u16 AsH[2 * TM * 32], BsH[2 * TN * 32], BsL[2 * TN * 32];
  int t = threadIdx.x;
  int lane = t & 63;
  int w = t >> 6;
  int wr = w / WN, wc = w % WN;
  int l15 = lane & 15, l16 = lane >> 4;
  int HW = Hout * Wout;
  int row0 = blockIdx.x * TM;
  int col0 = blockIdx.y * TN;
  const u16* Afh = Ah + (long)blockIdx.z * a_fstride;

  int rs = t >> 2;
  int cs = (t & 3) * 8;
  long abase[WM];
#pragma unroll
  for (int c = 0; c < WM; ++c) {
    int s = row0 + rs + 64 * c;
    if (s >= HW) s = HW - 1;
    int yo = s / Wout, xo = s - yo * Wout;
    int yb = yo * S - pad + Poff, xb = xo * S - pad + Poff;
    abase[c] = ((long)yb * Wp + xb) * Cin + cs;
  }
  long bbase[WN];
#pragma unroll
  for (int c = 0; c < WN; ++c)
    bbase[c] = (long)(col0 + rs + 64 * c) * Cin + cs;
  int ldst = w * 512;

  int nic = Cin >> 5;
  int NK = taps * nic;
  auto STAGE = [&](int kk, int buf) {
    int tap = kk / nic;
    int ic0 = (kk - tap * nic) << 5;
    int ky = tap / 3, kx = tap - ky * 3;
    long aoff = ((long)ky * DIL * Wp + kx * DIL) * Cin + ic0;
    long boff = (long)tap * Cout * Cin + ic0;
    u16* aB = AsH + buf * (TM * 32);
    u16* bhB = BsH + buf * (TN * 32);
    u16* blB = BsL + buf * (TN * 32);
#pragma unroll
    for (int c = 0; c < WM; ++c)
      gload16(Afh + abase[c] + aoff, aB + c * 2048 + ldst);
#pragma unroll
    for (int c = 0; c < WN; ++c) {
      gload16(Bh + bbase[c] + boff, bhB + c * 2048 + ldst);
      gload16(Bl + bbase[c] + boff, blB + c * 2048 + ldst);
    }
  };

  f32x4 acc[4][4];
#pragma unroll
  for (int m = 0; m < 4; ++m)
#pragma unroll
    for (int n = 0; n < 4; ++n) acc[m][n] = (f32x4){0.f, 0.f, 0.f, 0.f};

  STAGE(0, 0);
  __syncthreads();
  int cur = 0;
  for (int kk = 0; kk < NK; ++kk) {
    if (kk + 1 < NK) STAGE(kk + 1, cur ^ 1);
    const u16* aB = AsH + cur * (TM * 32);
    const u16* bhB = BsH + cur * (TN * 32);
    const u16* blB = BsL + cur * (TN * 32);
    bf16x8 ah[4];
#pragma unroll
    for (int m = 0; m < 4; ++m) {
      int rrow = wr * 64 + m * 16 + l15;
      ah[m] = *(const bf16x8*)(aB + rrow * 32 + l16 * 8);
    }
#pragma unroll
    for (int n = 0; n < 4; ++n) {
      int rcol = wc * 64 + n * 16 + l15;
      bf16x8 bh = *(const bf16x8*)(bhB + rcol * 32 + l16 * 8);
      bf16x8 bl = *(const bf16x8*)(blB + rcol * 32 + l16 * 8);
#pragma unroll
      for (int m = 0; m < 4; ++m) {
        acc[m][n] = MFMA(ah[m], bh, acc[m][n]);
        acc[m][n] = MFMA(ah[m], bl, acc[m][n]);
      }
    }
    __syncthreads();
    cur ^= 1;
  }

  float* yf = yout ? yout + (long)blockIdx.z * y_fstride : nullptr;
  u16* Ofh = Oh ? Oh + (long)blockIdx.z * o_fstride : nullptr;
  u16* Ofl = Ol ? Ol + (long)blockIdx.z * o_fstride : nullptr;
#pragma unroll
  for (int m = 0; m < 4; ++m) {
#pragma unroll
    for (int r = 0; r < 4; ++r) {
      int s = row0 + wr * 64 + m * 16 + l16 * 4 + r;
      if (s >= HW) continue;
      int yo = s / Wout, xo = s - yo * Wout;
      long clbase = 0;
      if (Ofh) clbase = ((long)(yo + PoffO) * WpO + (xo + PoffO)) * Cout;
#pragma unroll
      for (int n = 0; n < 4; ++n) {
        int oc = col0 + wc * 64 + n * 16 + l15;
        float v = acc[m][n][r] + bias[oc];
        if (act == ACT_LEAKY) v = v >= 0.f ? v : 0.2f * v;
        if (Ofh) {
          long off = clbase + oc;
          if (useres) v += bf2f(Ofh[off]) + bf2f(Ofl[off]);
          u16 h = f2bf(v);
          Ofh[off] = h;
          if (Ofl) Ofl[off] = f2bf(v - bf2f(h));
        }
        if (yf) yf[((long)oc * Hout + yo) * Wout + xo] = v;
      }
    }
  }
}

// ---------------------------------------------------------------------------
// Fused QKV 1x1 GEMM, 2-term, 2-phase dbuf. Tile 256x64, 4 waves.
// Token layout d = dm*64 + c. Q stores HI only (tql may be null).
// ---------------------------------------------------------------------------
__global__ __launch_bounds__(256) void qkv3_gemm_lds(
    const u16* __restrict__ Ah, const u16* __restrict__ Al, long a_fstride,
    int Wp, int Poff, const u16* __restrict__ qwh, const u16* __restrict__ qwl,
    const u16* __restrict__ kwh, const u16* __restrict__ kwl,
    const u16* __restrict__ vwh, const u16* __restrict__ vwl,
    const float* __restrict__ qbias, const float* __restrict__ kbias,
    const float* __restrict__ vbias, const int* __restrict__ nmap,
    const int* __restrict__ dmap, int ohow, int Dd, int pp, int NtokPad,
    float scale, u16* __restrict__ tqh, u16* __restrict__ tql,
    u16* __restrict__ tkh, u16* __restrict__ tkl, u16* __restrict__ tvh,
    u16* __restrict__ tvl) {
  __shared__ u16 AsH[2 * 256 * 32], BsH[2 * 64 * 32], BsL[2 * 64 * 32];
  int t = threadIdx.x;
  int lane = t & 63;
  int w = t >> 6;
  int l15 = lane & 15, l16 = lane >> 4;
  int row0 = blockIdx.x * 256;
  int frame = blockIdx.z;
  const u16* Afh = Ah + (long)frame * a_fstride;

  int rs = t >> 2;
  int cs = (t & 3) * 8;
  long abase[4];
#pragma unroll
  for (int c = 0; c < 4; ++c) {
    int s = row0 + rs + 64 * c;
    if (s >= 4800) s = 4799;
    int yo = s / 160, xo = s - yo * 160;
    abase[c] = ((long)(yo + Poff) * Wp + (xo + Poff)) * 256 + cs;
  }
  long bbase = (long)rs * 256 + cs;
  int ldst = w * 512;

  for (int mat = 0; mat < 3; ++mat) {
    const u16* Bh = mat == 0 ? qwh : mat == 1 ? kwh : vwh;
    const u16* Bl = mat == 0 ? qwl : mat == 1 ? kwl : vwl;
    const float* bias = mat == 0 ? qbias : mat == 1 ? kbias : vbias;
    u16* tH = mat == 0 ? tqh : mat == 1 ? tkh : tvh;
    u16* tL = mat == 0 ? tql : mat == 1 ? tkl : tvl;

    auto STAGE = [&](int kk, int buf) {
      int ic0 = kk << 5;
      u16* aB = AsH + buf * (256 * 32);
      u16* bhB = BsH + buf * (64 * 32);
      u16* blB = BsL + buf * (64 * 32);
#pragma unroll
      for (int c = 0; c < 4; ++c)
        gload16(Afh + abase[c] + ic0, aB + c * 2048 + ldst);
      gload16(Bh + bbase + ic0, bhB + ldst);
      gload16(Bl + bbase + ic0, blB + ldst);
    };

    f32x4 acc[4][4];
#pragma unroll
    for (int m = 0; m < 4; ++m)
#pragma unroll
      for (int n = 0; n < 4; ++n) acc[m][n] = (f32x4){0.f, 0.f, 0.f, 0.f};

    STAGE(0, 0);
    __syncthreads();
    int cur = 0;
    for (int kk = 0; kk < 8; ++kk) {
      if (kk + 1 < 8) STAGE(kk + 1, cur ^ 1);
      const u16* aB = AsH + cur * (256 * 32);
      const u16* bhB = BsH + cur * (64 * 32);
      const u16* blB = BsL + cur * (64 * 32);
      bf16x8 ah[4];
#pragma unroll
      for (int m = 0; m < 4; ++m) {
        int rrow = w * 64 + m * 16 + l15;
        ah[m] = *(const bf16x8*)(aB + rrow * 32 + l16 * 8);
      }
#pragma unroll
      for (int n = 0; n < 4; ++n) {
        int rcol = n * 16 + l15;
        bf16x8 bh = *(const bf16x8*)(bhB + rcol * 32 + l16 * 8);
        bf16x8 bl = *(const bf16x8*)(blB + rcol * 32 + l16 * 8);
#pragma unroll
        for (int m = 0; m < 4; ++m) {
          acc[m][n] = MFMA(ah[m], bh, acc[m][n]);
          acc[m][n] = MFMA(ah[m], bl, acc[m][n]);
        }
      }
      __syncthreads();
      cur ^= 1;
    }

#pragma unroll
    for (int m = 0; m < 4; ++m) {
#pragma unroll
      for (int r = 0; r < 4; ++r) {
        int s = row0 + w * 64 + m * 16 + l16 * 4 + r;
        if (s >= 4800) continue;
        int nm = nmap[s], dm = dmap[s];
        int ntok = frame * ohow + nm;
#pragma unroll
        for (int n = 0; n < 4; ++n) {
          int c = n * 16 + l15;
          float v = acc[m][n][r] + bias[c];
          if (mat == 0) v *= scale;
          int d = dm * 64 + c;
          long off = (mat == 2) ? ((long)d * NtokPad + ntok)
                                : ((long)ntok * Dd + d);
          u16 h = f2bf(v);
          tH[off] = h;
          if (mat != 0) tL[off] = f2bf(v - bf2f(h));
        }
      }
    }
  }
}

// ---------------------------------------------------------------------------
// Attention GEMM, 2-term Ah*(Bh+Bl), 2-phase dbuf. Tile 128x128. Serves BOTH
// QK (A=Q hi tokens) and PV (A=bf16 P). mode 0: fp32 out; mode 1: CL scatter.
// ---------------------------------------------------------------------------
__global__ __launch_bounds__(256) void attn_gemm_lds(
    const u16* __restrict__ Ah, const u16* __restrict__ Al, int lda, int Mrows,
    const u16* __restrict__ Bh, const u16* __restrict__ Bl, int ldb,
    int Nclamp, int Kpart, int Nvalid, int mode, float* outf, int ldo,
    long partstride, u16* __restrict__ Oh, u16* __restrict__ Ol,
    const int* __restrict__ rowbase, const int* __restrict__ doff) {
  __shared__ u16 AsH[2 * 128 * 32], BsH[2 * 128 * 32], BsL[2 * 128 * 32];
  int t = threadIdx.x;
  int lane = t & 63;
  int w = t >> 6;
  int wc = w & 1, wr = w >> 1;
  int l15 = lane & 15, l16 = lane >> 4;
  int row0 = blockIdx.x * 128;
  int col0 = blockIdx.y * 128;
  int kbase = blockIdx.z * Kpart;
  if (outf) outf += (long)blockIdx.z * partstride;

  int rs = t >> 2;
  int cs = (t & 3) * 8;
  long abase[2], bbase[2];
#pragma unroll
  for (int c = 0; c < 2; ++c) {
    int sr = row0 + rs + 64 * c;
    if (sr >= Mrows) sr = Mrows - 1;
    abase[c] = (long)sr * lda + cs;
    int cc = col0 + rs + 64 * c;
    if (cc >= Nclamp) cc = Nclamp - 1;
    bbase[c] = (long)cc * ldb + cs;
  }
  int ldst = w * 512;

  int NK = Kpart >> 5;
  auto STAGE = [&](int kk, int buf) {
    long k = kbase + ((long)kk << 5);
    u16* aB = AsH + buf * (128 * 32);
    u16* bhB = BsH + buf * (128 * 32);
    u16* blB = BsL + buf * (128 * 32);
#pragma unroll
    for (int c = 0; c < 2; ++c) {
      gload16(Ah + abase[c] + k, aB + c * 2048 + ldst);
      gload16(Bh + bbase[c] + k, bhB + c * 2048 + ldst);
      gload16(Bl + bbase[c] + k, blB + c * 2048 + ldst);
    }
  };

  f32x4 acc[4][4];
#pragma unroll
  for (int m = 0; m < 4; ++m)
#pragma unroll
    for (int n = 0; n < 4; ++n) acc[m][n] = (f32x4){0.f, 0.f, 0.f, 0.f};

  STAGE(0, 0);
  __syncthreads();
  int cur = 0;
  for (int kk = 0; kk < NK; ++kk) {
    if (kk + 1 < NK) STAGE(kk + 1, cur ^ 1);
    const u16* aB = AsH + cur * (128 * 32);
    const u16* bhB = BsH + cur * (128 * 32);
    const u16* blB = BsL + cur * (128 * 32);
    bf16x8 ah[4];
#pragma unroll
    for (int m = 0; m < 4; ++m) {
      int rrow = wr * 64 + m * 16 + l15;
      ah[m] = *(const bf16x8*)(aB + rrow * 32 + l16 * 8);
    }
#pragma unroll
    for (int n = 0; n < 4; ++n) {
      int rcol = wc * 64 + n * 16 + l15;
      bf16x8 bh = *(const bf16x8*)(bhB + rcol * 32 + l16 * 8);
      bf16x8 bl = *(const bf16x8*)(blB + rcol * 32 + l16 * 8);
#pragma unroll
      for (int m = 0; m < 4; ++m) {
        acc[m][n] = MFMA(ah[m], bh, acc[m][n]);
        acc[m][n] = MFMA(ah[m], bl, acc[m][n]);
      }
    }
    __syncthreads();
    cur ^= 1;
  }

#pragma unroll
  for (int m = 0; m < 4; ++m) {
#pragma unroll
    for (int r = 0; r < 4; ++r) {
      int sr = row0 + wr * 64 + m * 16 + l16 * 4 + r;
      if (sr >= Mrows) continue;
#pragma unroll
      for (int n = 0; n < 4; ++n) {
        int c = col0 + wc * 64 + n * 16 + l15;
        if (c >= Nvalid) continue;
        float v = acc[m][n][r];
        if (mode == 0) {
          outf[(long)sr * ldo + c] = v;
        } else {
          long off = (long)rowbase[sr] + doff[c];
          u16 h = f2bf(v);
          Oh[off] = h;
          if (Ol) Ol[off] = f2bf(v - bf2f(h));
        }
      }
    }
  }
}

// ---------------------------------------------------------------------------
__global__ __launch_bounds__(256) void reduce_scatter(
    const float* __restrict__ parts, int nparts, long pstride, int rows, int N,
    int mode, float* outf, u16* __restrict__ Oh, u16* __restrict__ Ol,
    const int* __restrict__ rowbase, const int* __restrict__ doff) {
  long gid = (long)blockIdx.x * 256 + threadIdx.x;
  long tot = (long)rows * N;
  if (gid >= tot) return;
  float s = 0.f;
  for (int p = 0; p < nparts; ++p) s += parts[p * pstride + gid];
  if (mode == 0) {
    outf[gid] = s;
  } else {
    int r = (int)(gid / N), c = (int)(gid % N);
    long off = (long)rowbase[r] + doff[c];
    u16 h = f2bf(s);
    Oh[off] = h;
    if (Ol) Ol[off] = f2bf(s - bf2f(h));
  }
}

// ---------------------------------------------------------------------------
// Row softmax: reads fp32 scores (stride NtokPad), writes bf16 P (stride
// NtokPad), zero pad. f2bf rounding == PV's previous in-register conversion.
// ---------------------------------------------------------------------------
__global__ __launch_bounds__(256) void softmax_bf(const float* __restrict__ S,
                                                  u16* __restrict__ P,
                                                  int Ntok, int NtokPad) {
  int row = blockIdx.x;
  const float* p = S + (long)row * NtokPad;
  u16* q = P + (long)row * NtokPad;
  __shared__ float red[256];
  int t = threadIdx.x;
  float m = -1e30f;
  for (int i = t; i < Ntok; i += 256) m = fmaxf(m, p[i]);
  red[t] = m;
  __syncthreads();
  for (int s = 128; s > 0; s >>= 1) {
    if (t < s) red[t] = fmaxf(red[t], red[t + s]);
    __syncthreads();
  }
  m = red[0];
  __syncthreads();
  float sum = 0.f;
  for (int i = t; i < Ntok; i += 256) sum += __expf(p[i] - m);
  red[t] = sum;
  __syncthreads();
  for (int s = 128; s > 0; s >>= 1) {
    if (t < s) red[t] += red[t + s];
    __syncthreads();
  }
  float inv = 1.f / red[0];
  for (int i = t; i < Ntok; i += 256) q[i] = f2bf(__expf(p[i] - m) * inv);
  for (int i = Ntok + t; i < NtokPad; i += 256) q[i] = 0;
}

// ---------------------------------------------------------------------------
__global__ __launch_bounds__(256) void wt_build(const float* __restrict__ w,
                                                int Cout, int Cin, int taps,
                                                u16* __restrict__ Wh,
                                                u16* __restrict__ Wl) {
  long gid = (long)blockIdx.x * 256 + threadIdx.x;
  long tot = (long)taps * Cout * Cin;
  if (gid >= tot) return;
  int ic = (int)(gid % Cin);
  long r = gid / Cin;
  int oc = (int)(r % Cout);
  int tap = (int)(r / Cout);
  float v = w[((long)oc * Cin + ic) * taps + tap];
  splitw(v, &Wh[gid], &Wl[gid]);
}

// build to/ff1/ff2 weight splits (256x256x9 each) in one dispatch
__global__ __launch_bounds__(256) void wt3_build(const float* __restrict__ w0,
                                                 const float* __restrict__ w1,
                                                 const float* __restrict__ w2,
                                                 u16* __restrict__ base) {
  long gid = (long)blockIdx.x * 256 + threadIdx.x;
  if (gid >= 3L * 589824) return;
  int mat = (int)(gid / 589824);
  int idx = (int)(gid - (long)mat * 589824);
  const float* w = mat == 0 ? w0 : mat == 1 ? w1 : w2;
  int ic = idx & 255;
  int r = idx >> 8;
  int oc = r & 255;
  int tap = r >> 8;
  float v = w[((long)oc * 256 + ic) * 9 + tap];
  u16* dst = base + (long)mat * 1179648;
  splitw(v, &dst[idx], &dst[589824 + idx]);
}

// fused q/k/v 1x1 weight split build, ALL 4 groups in one dispatch.
__global__ __launch_bounds__(256) void wtqkv_build_all(
    const float* __restrict__ wq, const float* __restrict__ wk,
    const float* __restrict__ wv, u16* __restrict__ qh, u16* __restrict__ ql,
    u16* __restrict__ kh, u16* __restrict__ kl, u16* __restrict__ vh,
    u16* __restrict__ vl) {
  int gid = blockIdx.x * 256 + threadIdx.x;
  if (gid >= 4 * 64 * 256) return;
  int ic = gid & 255;
  int c = (gid >> 8) & 63;
  int g = gid >> 14;
  long src = (long)(g * 64 + c) * 256 + ic;
  splitw(wq[src], &qh[gid], &ql[gid]);
  splitw(wk[src], &kh[gid], &kl[gid]);
  splitw(wv[src], &vh[gid], &vl[gid]);
}

// ---------------------------------------------------------------------------
__global__ __launch_bounds__(256) void maps_build(int ph, int pw, int ow,
                                                  int* __restrict__ nmap,
                                                  int* __restrict__ dmap) {
  int s = blockIdx.x * 256 + threadIdx.x;
  if (s >= 4800) return;
  int y = s / 160, x = s - y * 160;
  int i = y / ph, yy = y - i * ph;
  int j = x / pw, xx = x - j * pw;
  nmap[s] = i * ow + j;
  dmap[s] = yy * pw + xx;
}

// d = dm*64 + ch (channels innermost). doff[d] contiguous in ch.
__global__ __launch_bounds__(256) void luts_build(int ph, int pw, int ohow,
                                                  int ow, int pp, int Ntok,
                                                  int Dd, int gbase,
                                                  int* __restrict__ rowbase,
                                                  int* __restrict__ doff) {
  int gid = blockIdx.x * 256 + threadIdx.x;
  if (gid < Ntok) {
    int tt = gid / ohow, rem = gid - tt * ohow;
    int i = rem / ow, j = rem - i * ow;
    rowbase[gid] =
        tt * (32 * 162 * 256) + ((i * ph + 1) * 162 + (j * pw + 1)) * 256;
  }
  if (gid < Dd) {
    int ch = gid & 63;
    int dm = gid >> 6;
    int yy = dm / pw, xx = dm - yy * pw;
    doff[gid] = (yy * 162 + xx) * 256 + gbase + ch;
  }
}

// ---------------------------------------------------------------------------
// Bilinear x2 upsample (align_corners) CL hi/lo -> CL, full padded write.
// ol may be null. blockIdx.z = frame.
// ---------------------------------------------------------------------------
__global__ __launch_bounds__(256) void up_cl2cl_pad(
    const u16* __restrict__ sh, const u16* __restrict__ sl,
    u16* __restrict__ oh, u16* __restrict__ ol, long s_fs, long o_fs, int C,
    int H, int W, int Wps, int Poffs, int Hp, int Wpo, int Poffo) {
  sh += (long)blockIdx.z * s_fs;
  sl += (long)blockIdx.z * s_fs;
  oh += (long)blockIdx.z * o_fs;
  if (ol) ol += (long)blockIdx.z * o_fs;
  int Ho = 2 * H, Wo = 2 * W;
  long tot = (long)Hp * Wpo * C;
  long gid = (long)blockIdx.x * 256 + threadIdx.x;
  if (gid >= tot) return;
  int c = (int)(gid % C);
  long r = gid / C;
  int xp = (int)(r % Wpo);
  int yp = (int)(r / Wpo);
  int x = xp - Poffo, y = yp - Poffo;
  float v = 0.f;
  if ((unsigned)x < (unsigned)Wo && (unsigned)y < (unsigned)Ho) {
    float fy = (float)(y * (H - 1)) / (float)(Ho - 1);
    float fx = (float)(x * (W - 1)) / (float)(Wo - 1);
    int y0 = (int)fy, x0 = (int)fx;
    int y1 = min(y0 + 1, H - 1), x1 = min(x0 + 1, W - 1);
    float wy = fy - y0, wx = fx - x0;
    auto rd = [&](int cy, int cx) {
      long o = ((long)(cy + Poffs) * Wps + (cx + Poffs)) * C + c;
      return bf2f(sh[o]) + bf2f(sl[o]);
    };
    float r0 = rd(y0, x0) * (1.f - wx) + rd(y0, x1) * wx;
    float r1 = rd(y1, x0) * (1.f - wx) + rd(y1, x1) * wx;
    v = r0 * (1.f - wy) + r1 * wy;
  }
  u16 h = f2bf(v);
  oh[gid] = h;
  if (ol) ol[gid] = f2bf(v - bf2f(h));
}

// ---------------------------------------------------------------------------
extern "C" void kernel_launch(void* const* d_in, const int* in_sizes, int n_in,
                              void* d_out, int out_size, void* d_ws,
                              size_t ws_size, hipStream_t stream) {
  const float* input = (const float*)d_in[0];
  const float* enc_w0 = (const float*)d_in[1];
  const float* enc_b0 = (const float*)d_in[2];
  const float* enc_w1 = (const float*)d_in[3];
  const float* enc_b1 = (const float*)d_in[4];
  const float* enc_w2 = (const float*)d_in[5];
  const float* enc_b2 = (const float*)d_in[6];
  const float* enc_w3 = (const float*)d_in[7];
  const float* enc_b3 = (const float*)d_in[8];
  const float* tq_w = (const float*)d_in[9];
  const float* tq_b = (const float*)d_in[10];
  const float* tk_w = (const float*)d_in[11];
  const float* tk_b = (const float*)d_in[12];
  const float* tv_w = (const float*)d_in[13];
  const float* tv_b = (const float*)d_in[14];
  const float* to_w = (const float*)d_in[15];
  const float* to_b = (const float*)d_in[16];
  const float* tf1_w = (const float*)d_in[17];
  const float* tf1_b = (const float*)d_in[18];
  const float* tf2_w = (const float*)d_in[19];
  const float* tf2_b = (const float*)d_in[20];
  const float* d0_w = (const float*)d_in[21];
  const float* d0_b = (const float*)d_in[22];
  const float* d1_w = (const float*)d_in[23];
  const float* d1_b = (const float*)d_in[24];
  const float* d2_w = (const float*)d_in[25];
  const float* d2_b = (const float*)d_in[26];
  const float* d3_w = (const float*)d_in[27];
  const float* d3_b = (const float*)d_in[28];
  float* out = (float*)d_out;

  // -------- workspace layout --------
  unsigned char* wsb = (unsigned char*)d_ws;
  size_t off = 0;
  auto alloc = [&](size_t bytes) {
    void* p = wsb + off;
    off = (off + bytes + 255) & ~(size_t)255;
    return p;
  };
  const long XCL_E = 22839296L;   // 16*34*164*256
  const long XCL2_E = 21233664L;  // 16*32*162*256
  const long QT_E = 4915200L;
  const long VT_E = 5111808L;
  u16* XCLh = (u16*)alloc(XCL_E * 2);
  u16* XCLl = (u16*)alloc(XCL_E * 2);
  u16* XCL2h = (u16*)alloc(XCL2_E * 2);
  u16* XCL2l = (u16*)alloc(XCL2_E * 2);
  u16* qth = (u16*)alloc(QT_E * 2);   // Q hi only (qtl dropped since R13)
  u16* kth = (u16*)alloc(QT_E * 2);
  u16* ktl = (u16*)alloc(QT_E * 2);
  u16* vth = (u16*)alloc(VT_E * 2);
  u16* vtl = (u16*)alloc(VT_E * 2);
  int* nmapA = (int*)alloc(4 * 4800 * 4);
  int* dmapA = (int*)alloc(4 * 4800 * 4);
  int* rowbaseA = (int*)alloc(7120 * 4);
  int* doffA = (int*)alloc(93248 * 4);
  u16* qwh = (u16*)alloc(65536 * 2);
  u16* qwl = (u16*)alloc(65536 * 2);
  u16* kwh = (u16*)alloc(65536 * 2);
  u16* kwl = (u16*)alloc(65536 * 2);
  u16* vwh = (u16*)alloc(65536 * 2);
  u16* vwl = (u16*)alloc(65536 * 2);
  size_t fixed_end = off;
  size_t avail = ws_size > fixed_end ? ws_size - fixed_end : 0;
  size_t SCB = avail > 4096 ? avail - 4096 : 0;
  if (SCB > 157286400UL) SCB = 157286400UL;
  float* scores = (float*)alloc(SCB);
  size_t need = off;
  if (ws_size < need) return;  // fail loud, not crash
  if (SCB < 8388608UL) return; // need >=8MB (wt3 region + min chunks)

  // encoder weight splits + trunk wt3 region overlay the scores region
  u16* Wth = (u16*)scores;
  u16* Wtl = Wth + 589824;
  u16* W3 = (u16*)scores;

  // ---- decoder buffers: overlay XCL2+token+scores region ----
  unsigned char* decbase = (unsigned char*)XCL2h;
  u16* dec0inH = (u16*)(decbase + 0);
  u16* dec0outH = (u16*)(decbase + 81772544);
  u16* dec1outH = (u16*)(decbase + 122658816);
  u16* dec1outL = (u16*)(decbase + 132880384);
  u16* dec2inH = (u16*)(decbase + 0);
  float* dec2out = (float*)(decbase + 40101888);
  u16* Wd0h = (u16*)(decbase + 143101952);
  u16* Wd0l = Wd0h + 294912;
  u16* W1h = Wd0l + 294912;
  u16* W1l = W1h + 73728;
  u16* W2h = W1l + 73728;
  u16* W2l = W2h + 36864;
  const long D0IN_FS = 5110784, D0OUT_FS = 2555392, D1OUT_FS = 1277696;
  const long D2IN_FS = 5012736, D2OUT_FS = 4915200;

  const long FS_TR = 1427456;  // 34*164*256
  const long FS_T2 = 1327104;  // 32*162*256 == 64*324*64
  const long FS_E2 = 713728;   // 34*164*128

  static const int PWa[4] = {80, 32, 10, 5};
  static const int PHa[4] = {15, 6, 5, 3};
  static const int rbOff[4] = {0, 64, 464, 2000};
  static const int doOff[4] = {0, 76800, 89088, 92288};

  // -------- encoder --------
  hipMemsetAsync(XCLh, 0, XCL_E * 2, stream);
  hipMemsetAsync(XCL2h, 0, XCL2_E * 2, stream);
  hipMemsetAsync(vth, 0, VT_E * 2, stream);
  hipMemsetAsync(vtl, 0, VT_E * 2, stream);
  conv_enc0_cl<<<9600, 256, 0, stream>>>(input, enc_w0, enc_b0, XCL2h);
  {  // enc1
    wt_build<<<cdivu(9L * 64 * 64, 256), 256, 0, stream>>>(enc_w1, 64, 64, 9,
                                                           Wth, Wtl);
    conv_gemm_lds<4, 1><<<dim3(75, 1, 16), 256, 0, stream>>>(
        XCL2h, nullptr, Wth, Wtl, enc_b1, 64, 64, 60, 320, 324, 2, 1, 1, 1, 9,
        FS_T2, ACT_LEAKY, nullptr, 0, XCLh, nullptr, FS_T2, 324, 2, 0);
  }
  hipMemsetAsync(XCL2h, 0, XCL2_E * 2, stream);
  {  // enc2
    wt_build<<<cdivu(9L * 128 * 64, 256), 256, 0, stream>>>(enc_w2, 128, 64, 9,
                                                            Wth, Wtl);
    conv_gemm_lds<2, 2><<<dim3(38, 1, 16), 256, 0, stream>>>(
        XCLh, nullptr, Wth, Wtl, enc_b2, 64, 128, 30, 160, 324, 2, 2, 1, 1, 9,
        FS_T2, ACT_LEAKY, nullptr, 0, XCL2h, nullptr, FS_E2, 164, 2, 0);
  }
  hipMemsetAsync(XCLh, 0, XCL_E * 2, stream);
  hipMemsetAsync(XCLl, 0, XCL_E * 2, stream);
  {  // enc3: trunk XCL hi+lo (residual master)
    wt_build<<<cdivu(9L * 256 * 128, 256), 256, 0, stream>>>(enc_w3, 256, 128,
                                                             9, Wth, Wtl);
    conv_gemm_lds<2, 2><<<dim3(38, 2, 16), 256, 0, stream>>>(
        XCL2h, nullptr, Wth, Wtl, enc_b3, 128, 256, 30, 160, 164, 2, 1, 1, 1,
        9, FS_E2, ACT_LEAKY, nullptr, 0, XCLh, XCLl, FS_TR, 164, 2, 0);
  }
  hipMemsetAsync(XCL2h, 0, XCL2_E * 2, stream);

  // -------- token maps / scatter LUTs --------
  for (int g = 0; g < 4; ++g) {
    int ph = PHa[g], pw = PWa[g];
    int ohh = 30 / ph, oww = 160 / pw;
    int Ntok = 16 * ohh * oww, Dd = 64 * ph * pw, pp = ph * pw;
    maps_build<<<19, 256, 0, stream>>>(ph, pw, oww, nmapA + g * 4800,
                                       dmapA + g * 4800);
    int mx = Ntok > Dd ? Ntok : Dd;
    luts_build<<<cdivu(mx, 256), 256, 0, stream>>>(
        ph, pw, ohh * oww, oww, pp, Ntok, Dd, g * 64, rowbaseA + rbOff[g],
        doffA + doOff[g]);
  }

  // -------- transformer stack --------
  for (int l = 0; l < 8; ++l) {
    wtqkv_build_all<<<256, 256, 0, stream>>>(
        tq_w + (long)l * 65536, tk_w + (long)l * 65536,
        tv_w + (long)l * 65536, qwh, qwl, kwh, kwl, vwh, vwl);

    for (int g = 0; g < 4; ++g) {
      int ph = PHa[g], pw = PWa[g];
      int ohh = 30 / ph, oww = 160 / pw;
      int ohow = ohh * oww;
      int Ntok = 16 * ohow, Dd = 64 * ph * pw, pp = ph * pw;
      int NtokPad = (Ntok + 31) & ~31;
      float scale = 1.0f / sqrtf((float)Dd);
      const int* nmap = nmapA + g * 4800;
      const int* dmap = dmapA + g * 4800;
      const int* rowbase = rowbaseA + rbOff[g];
      const int* doffp = doffA + doOff[g];

      qkv3_gemm_lds<<<dim3(19, 1, 16), 256, 0, stream>>>(
          XCLh, nullptr, FS_TR, 164, 2, qwh + g * 16384, qwl + g * 16384,
          kwh + g * 16384, kwl + g * 16384, vwh + g * 16384, vwl + g * 16384,
          tq_b + l * 256 + g * 64, tk_b + l * 256 + g * 64,
          tv_b + l * 256 + g * 64, nmap, dmap, ohow, Dd, pp, NtokPad, scale,
          qth, nullptr, kth, ktl, vth, vtl);

      if (g == 0) {
        float* scoresR = scores + 131072;
        u16* pbf0 = (u16*)(scoresR + 4096);
        attn_gemm_lds<<<dim3(1, 1, 32), 256, 0, stream>>>(
            qth, nullptr, Dd, 64, kth, ktl, Dd, 64, 2400, 64, 0, scores, 64,
            4096, nullptr, nullptr, nullptr, nullptr);
        reduce_scatter<<<16, 256, 0, stream>>>(scores, 32, 4096, 64, 64, 0,
                                               scoresR, nullptr, nullptr,
                                               nullptr, nullptr);
        softmax_bf<<<64, 256, 0, stream>>>(scoresR, pbf0, 64, 64);
        attn_gemm_lds<<<dim3(1, 600, 1), 256, 0, stream>>>(
            pbf0, nullptr, 64, 64, vth, vtl, 64, Dd, 64, Dd, 1, nullptr, 0, 0,
            XCL2h, nullptr, rowbase, doffp);
      } else {
        // bytes/row: scores fp32 (4*Pad) + P bf16 (2*Pad) + g3 partials 15360
        long denomB = 6L * NtokPad + (g == 3 ? 15360 : 0);
        long capB = ((long)SCB - 65536) / denomB;
        int chunk = (int)(capB & ~127L);
        if (chunk < 128) chunk = 128;
        if (chunk > Ntok) chunk = Ntok;
        u16* Pbf = (u16*)(scores + (long)chunk * NtokPad);
        float* partials = (float*)(Pbf + (long)chunk * NtokPad);
        for (int r0 = 0; r0 < Ntok; r0 += chunk) {
          int rows = Ntok - r0 < chunk ? Ntok - r0 : chunk;
          attn_gemm_lds<<<dim3(cdivu(rows, 128), cdivu(Ntok, 128), 1), 256, 0,
                          stream>>>(qth + (long)r0 * Dd, nullptr, Dd, rows,
                                    kth, ktl, Dd, Ntok, Dd, Ntok, 0, scores,
                                    NtokPad, 0, nullptr, nullptr, nullptr,
                                    nullptr);
          softmax_bf<<<rows, 256, 0, stream>>>(scores, Pbf, Ntok, NtokPad);
          if (g == 3) {
            attn_gemm_lds<<<dim3(cdivu(rows, 128), 8, 4), 256, 0, stream>>>(
                Pbf, nullptr, NtokPad, rows, vth, vtl, NtokPad, Dd, 1280, Dd,
                0, partials, 960, (long)rows * 960, nullptr, nullptr, nullptr,
                nullptr);
            reduce_scatter<<<cdivu((long)rows * 960, 256), 256, 0, stream>>>(
                partials, 4, (long)rows * 960, rows, 960, 1, nullptr, XCL2h,
                nullptr, rowbase + r0, doffp);
          } else {
            attn_gemm_lds<<<dim3(cdivu(rows, 128), Dd / 128, 1), 256, 0,
                            stream>>>(Pbf, nullptr, NtokPad, rows, vth, vtl,
                                      NtokPad, Dd, NtokPad, Dd, 1, nullptr, 0,
                                      0, XCL2h, nullptr, rowbase + r0, doffp);
          }
        }
      }
    }

    wt3_build<<<6912, 256, 0, stream>>>(to_w + (long)l * 589824,
                                        tf1_w + (long)l * 589824,
                                        tf2_w + (long)l * 589824, W3);
    // out-conv: reads XCL2 hi; writes XCL hi+lo with residual
    conv_gemm_lds<2, 2><<<dim3(38, 2, 16), 256, 0, stream>>>(
        XCL2h, nullptr, W3, W3 + 589824, to_b + l * 256, 256, 256, 30, 160,
        162, 1, 1, 1, 1, 9, FS_T2, ACT_LEAKY, nullptr, 0, XCLh, XCLl, FS_TR,
        164, 2, 1);
    // ff1: writes XCL2 hi-only
    conv_gemm_lds<2, 2><<<dim3(38, 2, 16), 256, 0, stream>>>(
        XCLh, nullptr, W3 + 1179648, W3 + 1769472, tf1_b + l * 256, 256, 256,
        30, 160, 164, 2, 1, 2, 2, 9, FS_TR, ACT_LEAKY, nullptr, 0, XCL2h,
        nullptr, FS_T2, 162, 1, 0);
    // ff2 + residual: writes XCL hi+lo
    conv_gemm_lds<2, 2><<<dim3(38, 2, 16), 256, 0, stream>>>(
        XCL2h, nullptr, W3 + 2359296, W3 + 2949120, tf2_b + l * 256, 256, 256,
        30, 160, 162, 1, 1, 1, 1, 9, FS_T2, ACT_LEAKY, nullptr, 0, XCLh, XCLl,
        FS_TR, 164, 2, 1);
  }

  // -------- decoder: 4-frame front half, 2-frame back half --------
  hipMemsetAsync(decbase, 0, 144723968, stream);
  wt_build<<<cdivu(9L * 128 * 256, 256), 256, 0, stream>>>(d0_w, 128, 256, 9,
                                                           Wd0h, Wd0l);
  wt_build<<<cdivu(9L * 64 * 128, 256), 256, 0, stream>>>(d1_w, 64, 128, 9,
                                                          W1h, W1l);
  wt_build<<<cdivu(9L * 64 * 64, 256), 256, 0, stream>>>(d2_w, 64, 64, 9, W2h,
                                                         W2l);
  for (int f = 0; f < 16; f += 4) {
    up_cl2cl_pad<<<dim3(cdivu(62L * 322 * 256, 256), 1, 4), 256, 0, stream>>>(
        XCLh + (long)f * FS_TR, XCLl + (long)f * FS_TR, dec0inH, nullptr,
        FS_TR, D0IN_FS, 256, 30, 160, 164, 2, 62, 322, 1);
    conv_gemm_lds<2, 2><<<dim3(150, 1, 4), 256, 0, stream>>>(
        dec0inH, nullptr, Wd0h, Wd0l, d0_b, 256, 128, 60, 320, 322, 1, 1, 1, 1,
        9, D0IN_FS, ACT_LEAKY, nullptr, 0, dec0outH, nullptr, D0OUT_FS, 322, 1,
        0);
    conv_gemm_lds<4, 1><<<dim3(75, 1, 4), 256, 0, stream>>>(
        dec0outH, nullptr, W1h, W1l, d1_b, 128, 64, 60, 320, 322, 1, 1, 1, 1,
        9, D0OUT_FS, ACT_LEAKY, nullptr, 0, dec1outH, dec1outL, D1OUT_FS, 322,
        1, 0);
    for (int ff = 0; ff < 4; ff += 2) {
      up_cl2cl_pad<<<dim3(cdivu(122L * 642 * 64, 256), 1, 2), 256, 0,
                     stream>>>(dec1outH + (long)ff * D1OUT_FS,
                               dec1outL + (long)ff * D1OUT_FS, dec2inH,
                               nullptr, D1OUT_FS, D2IN_FS, 64, 60, 320, 322, 1,
                               122, 642, 1);
      conv_gemm_lds<4, 1><<<dim3(300, 1, 2), 256, 0, stream>>>(
          dec2inH, nullptr, W2h, W2l, d2_b, 64, 64, 120, 640, 642, 1, 1, 1, 1,
          9, D2IN_FS, ACT_LEAKY, dec2out, D2OUT_FS, nullptr, nullptr, 0, 0, 0,
          0);
      long tot = 2L * 3 * 120 * 80;
      conv2d_k<3, 1, 1><<<cdivu(tot, 256), 256, 0, stream>>>(
          dec2out, d3_w, d3_b, out + (long)(f + ff) * 230400, nullptr, nullptr,
          0, 0, 0, 2, 64, 120, 640, 3, 120, 640, 1, ACT_TANH);
    }
  }
}